// Round 1
// baseline (1833.663 us; speedup 1.0000x reference)
//
#include <hip/hip_runtime.h>
#include <hip/hip_bf16.h>

// Problem constants (fixed by the reference)
#define B_ROWS 16384
#define L_SEQ  32

// ---------- fast device math ----------
__device__ __forceinline__ float tanh_fast(float x) {
    // tanh(x) = 1 - 2/(exp(2x)+1); saturates correctly at +-inf via v_exp/v_rcp
    float e = __expf(2.0f * x);
    return 1.0f - __fdividef(2.0f, e + 1.0f);
}
__device__ __forceinline__ float gelu_exact(float x) {
    return 0.5f * x * (1.0f + erff(x * 0.70710678118654752440f));
}

// ---------- F(s, z): the 8->256(relu)->16(tanh) MLP contracted with dX ----------
// Lane `sub` (0..15 in its 16-lane group) owns hidden units j = sub + 16*t.
// G partials start at b2/16 so the 16-lane butterfly sums b2 exactly.
__device__ __forceinline__ void Ffunc(const float* __restrict__ sW1,
                                      const float* __restrict__ sW2T,
                                      int sub,
                                      const float (&zz)[8],
                                      const float (&b2s)[16],
                                      float d0, float d1,
                                      float (&k)[8])
{
    float G[16];
#pragma unroll
    for (int o = 0; o < 16; ++o) G[o] = b2s[o];

#pragma unroll 4
    for (int t = 0; t < 16; ++t) {
        const int j = sub + (t << 4);
        const float* wr = sW1 + j * 12;             // 48B rows: 2-way bank alias only
        float4 wa = *(const float4*)(wr);
        float4 wb = *(const float4*)(wr + 4);
        float h = wr[8];                            // b1 folded into row
        h = fmaf(wa.x, zz[0], h);
        h = fmaf(wa.y, zz[1], h);
        h = fmaf(wa.z, zz[2], h);
        h = fmaf(wa.w, zz[3], h);
        h = fmaf(wb.x, zz[4], h);
        h = fmaf(wb.y, zz[5], h);
        h = fmaf(wb.z, zz[6], h);
        h = fmaf(wb.w, zz[7], h);
        h = fmaxf(h, 0.0f);                         // relu
        const float* vr = sW2T + j * 20;            // 80B rows: 2-way bank alias only
        float4 v0 = *(const float4*)(vr);
        float4 v1 = *(const float4*)(vr + 4);
        float4 v2 = *(const float4*)(vr + 8);
        float4 v3 = *(const float4*)(vr + 12);
        G[0]  = fmaf(v0.x, h, G[0]);   G[1]  = fmaf(v0.y, h, G[1]);
        G[2]  = fmaf(v0.z, h, G[2]);   G[3]  = fmaf(v0.w, h, G[3]);
        G[4]  = fmaf(v1.x, h, G[4]);   G[5]  = fmaf(v1.y, h, G[5]);
        G[6]  = fmaf(v1.z, h, G[6]);   G[7]  = fmaf(v1.w, h, G[7]);
        G[8]  = fmaf(v2.x, h, G[8]);   G[9]  = fmaf(v2.y, h, G[9]);
        G[10] = fmaf(v2.z, h, G[10]);  G[11] = fmaf(v2.w, h, G[11]);
        G[12] = fmaf(v3.x, h, G[12]);  G[13] = fmaf(v3.y, h, G[13]);
        G[14] = fmaf(v3.z, h, G[14]);  G[15] = fmaf(v3.w, h, G[15]);
    }

    // butterfly-reduce each of the 16 partials across the 16-lane group
#pragma unroll
    for (int o = 0; o < 16; ++o) {
        float v = G[o];
        v += __shfl_xor(v, 1, 16);
        v += __shfl_xor(v, 2, 16);
        v += __shfl_xor(v, 4, 16);
        v += __shfl_xor(v, 8, 16);
        G[o] = v;
    }

    // g = tanh(G) reshaped (8,2); k[h] = g[h][0]*dX0 + g[h][1]*dX1
#pragma unroll
    for (int hh = 0; hh < 8; ++hh) {
        float ga = tanh_fast(G[2 * hh]);
        float gb = tanh_fast(G[2 * hh + 1]);
        k[hh] = fmaf(ga, d0, gb * d1);
    }
}

// ---------- Kernel 1: preprocessing + RK4 neural-ODE integration ----------
__global__ __launch_bounds__(256) void ode_kernel(
    const float* __restrict__ Xin, const float* __restrict__ Fin,
    const int*   __restrict__ fa_len,
    const float* __restrict__ Wi,  const float* __restrict__ bi,
    const float* __restrict__ W1g, const float* __restrict__ b1g,
    const float* __restrict__ W2g, const float* __restrict__ b2g,
    float* __restrict__ zT)
{
    __shared__ float sW1[256 * 12];     // [w0..w7, b1, pad, pad, pad]
    __shared__ float sW2T[256 * 20];    // W2 transposed, padded 16->20
    __shared__ float xm[16][32][4];     // per row: {fa, X, m_fa, m_X}

    const int tid = threadIdx.x;

    // stage weights (thread t handles hidden unit t)
    {
        const float* w = W1g + tid * 8;
        float* d = sW1 + tid * 12;
        *(float4*)(d)     = *(const float4*)(w);
        *(float4*)(d + 4) = *(const float4*)(w + 4);
        d[8] = b1g[tid];
#pragma unroll
        for (int o = 0; o < 16; ++o) sW2T[tid * 20 + o] = W2g[o * 256 + tid];
    }

    const int row_l = tid >> 4;
    const int sub   = tid & 15;
    const int row   = blockIdx.x * 16 + row_l;

    // ---- preprocessing (replicates push_zeros + fill exactly) ----
    const float* Xr = Xin + row * L_SEQ;
    const float* Fr = Fin + row * L_SEQ;
    float xr0 = Xr[sub], xr1 = Xr[sub + 16];
    float fr0 = Fr[sub], fr1 = Fr[sub + 16];
    const int   fl  = fa_len[row];
    const float flf = (float)fl;

    float s = xr0 + xr1;
    s += __shfl_xor(s, 1, 16);
    s += __shfl_xor(s, 2, 16);
    s += __shfl_xor(s, 4, 16);
    s += __shfl_xor(s, 8, 16);
    const float mean = s / flf;

    xm[row_l][sub][0]      = fr0; xm[row_l][sub][1]      = xr0;
    xm[row_l][sub + 16][0] = fr1; xm[row_l][sub + 16][1] = xr1;
    __syncthreads();

    const int shift = L_SEQ - fl;             // leading zeros after push_zeros
    int lsrc  = fl - 1 - shift;               // source of last_X in sorted array
    int lsrcC = lsrc < 0 ? 0 : lsrc;
    float lastX = (lsrc >= 0) ? (xm[row_l][lsrcC][1] / mean) : 0.0f;
    float lastF = xm[row_l][fl - 1][0];       // last_fa from ORIGINAL array

    float ff[2], xf[2];
#pragma unroll
    for (int u = 0; u < 2; ++u) {
        int p = sub + u * 16;
        int src = p - shift;
        int sc  = src < 0 ? 0 : src;
        float fraw = xm[row_l][sc][0];
        float xraw = xm[row_l][sc][1];
        ff[u] = (src >= 0) ? fraw : lastF;
        xf[u] = (src >= 0) ? (xraw / mean) : lastX;
    }
    __syncthreads();
#pragma unroll
    for (int u = 0; u < 2; ++u) {
        int p = sub + u * 16;
        xm[row_l][p][0] = ff[u];
        xm[row_l][p][1] = xf[u];
    }
    __syncthreads();
#pragma unroll
    for (int u = 0; u < 2; ++u) {
        int p = sub + u * 16;
        int q = (p == 0) ? 1 : p;             // m[0] = x[1]-x[0]
        float mf = xm[row_l][q][0] - xm[row_l][q - 1][0];
        float mX = xm[row_l][q][1] - xm[row_l][q - 1][1];
        xm[row_l][p][2] = mf;
        xm[row_l][p][3] = mX;
    }
    __syncthreads();

    // b2 pre-scaled by 1/16 (butterfly over 16 lanes restores it exactly)
    float b2s[16];
#pragma unroll
    for (int o = 0; o < 16; ++o) b2s[o] = b2g[o] * 0.0625f;

    // z0 = W_init @ x[0] + b_init
    float z[8];
    {
        float f0 = xm[row_l][0][0];
        float X0 = xm[row_l][0][1];
#pragma unroll
        for (int h = 0; h < 8; ++h)
            z[h] = fmaf(Wi[h * 2], f0, fmaf(Wi[h * 2 + 1], X0, bi[h]));
    }

    // ---- 31 intervals x 2 substeps of RK4 ----
#pragma unroll 1
    for (int i = 0; i < 31; ++i) {
        float4 A  = *(const float4*)(&xm[row_l][i][0]);
        float4 Bv = *(const float4*)(&xm[row_l][i + 1][0]);
        const float x0f = A.x,  x0X = A.y,  m0f = A.z,  m0X = A.w;
        const float x1f = Bv.x, x1X = Bv.y, m1f = Bv.z, m1X = Bv.w;

#pragma unroll 1
        for (int ssi = 0; ssi < 2; ++ssi) {
            const float s0 = 0.5f * (float)ssi;
            float da0, da1, db0, db1, dd0, dd1;
            {   // s = s0
                float sv = s0, s2 = sv * sv;
                float c0 = 6.f * s2 - 6.f * sv, c1 = 3.f * s2 - 4.f * sv + 1.f, c3 = 3.f * s2 - 2.f * sv;
                da0 = c0 * x0f + c1 * m0f - c0 * x1f + c3 * m1f;
                da1 = c0 * x0X + c1 * m0X - c0 * x1X + c3 * m1X;
            }
            {   // s = s0 + 0.25
                float sv = s0 + 0.25f, s2 = sv * sv;
                float c0 = 6.f * s2 - 6.f * sv, c1 = 3.f * s2 - 4.f * sv + 1.f, c3 = 3.f * s2 - 2.f * sv;
                db0 = c0 * x0f + c1 * m0f - c0 * x1f + c3 * m1f;
                db1 = c0 * x0X + c1 * m0X - c0 * x1X + c3 * m1X;
            }
            {   // s = s0 + 0.5
                float sv = s0 + 0.5f, s2 = sv * sv;
                float c0 = 6.f * s2 - 6.f * sv, c1 = 3.f * s2 - 4.f * sv + 1.f, c3 = 3.f * s2 - 2.f * sv;
                dd0 = c0 * x0f + c1 * m0f - c0 * x1f + c3 * m1f;
                dd1 = c0 * x0X + c1 * m0X - c0 * x1X + c3 * m1X;
            }

            float k[8], kacc[8], zz[8];
            Ffunc(sW1, sW2T, sub, z, b2s, da0, da1, k);      // k1
#pragma unroll
            for (int h = 0; h < 8; ++h) { kacc[h] = k[h]; zz[h] = fmaf(0.25f, k[h], z[h]); }
            Ffunc(sW1, sW2T, sub, zz, b2s, db0, db1, k);     // k2
#pragma unroll
            for (int h = 0; h < 8; ++h) { kacc[h] = fmaf(2.f, k[h], kacc[h]); zz[h] = fmaf(0.25f, k[h], z[h]); }
            Ffunc(sW1, sW2T, sub, zz, b2s, db0, db1, k);     // k3
#pragma unroll
            for (int h = 0; h < 8; ++h) { kacc[h] = fmaf(2.f, k[h], kacc[h]); zz[h] = fmaf(0.5f, k[h], z[h]); }
            Ffunc(sW1, sW2T, sub, zz, b2s, dd0, dd1, k);     // k4
#pragma unroll
            for (int h = 0; h < 8; ++h) { z[h] = fmaf(1.f / 12.f, kacc[h] + k[h], z[h]); }
        }
    }

    if (sub == 0) {
        float4 za = make_float4(z[0], z[1], z[2], z[3]);
        float4 zb = make_float4(z[4], z[5], z[6], z[7]);
        float4* dst = (float4*)(zT + row * 8);
        dst[0] = za; dst[1] = zb;
    }
}

// ---------- Kernel 2: gelu readout + T10 + X_out ----------
__global__ __launch_bounds__(256) void readout_kernel(
    const float* __restrict__ zT,
    const float* __restrict__ Fin,
    const float* __restrict__ TRv,
    const int*   __restrict__ fa_len,
    const float* __restrict__ Wr1, const float* __restrict__ br1,
    const float* __restrict__ Wr2, const float* __restrict__ br2,
    const float* __restrict__ Wr3, const float* __restrict__ br3,
    float* __restrict__ out)
{
    __shared__ float h1s[32][200];     // per-row h1
    __shared__ float w2s[40][200];     // Wr2 chunk (5 chunks of 40 rows)
    const int tid = threadIdx.x;
    const int g = tid >> 3, sub = tid & 7;
    const int row = blockIdx.x * 32 + g;

    float4 za = *(const float4*)(zT + row * 8);
    float4 zb = *(const float4*)(zT + row * 8 + 4);

    // h1 = gelu(z @ Wr1.T + br1); lane owns j = sub + 8t
#pragma unroll 5
    for (int t = 0; t < 25; ++t) {
        int j = sub + 8 * t;
        const float* w = Wr1 + j * 8;
        float4 wa = *(const float4*)(w);
        float4 wb = *(const float4*)(w + 4);
        float acc = br1[j];
        acc = fmaf(wa.x, za.x, acc);
        acc = fmaf(wa.y, za.y, acc);
        acc = fmaf(wa.z, za.z, acc);
        acc = fmaf(wa.w, za.w, acc);
        acc = fmaf(wb.x, zb.x, acc);
        acc = fmaf(wb.y, zb.y, acc);
        acc = fmaf(wb.z, zb.z, acc);
        acc = fmaf(wb.w, zb.w, acc);
        h1s[g][j] = gelu_exact(acc);
    }
    __syncthreads();

    float tacc = 0.0f;
    for (int c = 0; c < 5; ++c) {
        // load Wr2 rows [40c, 40c+40) — contiguous 8000 floats
        const float4* src4 = (const float4*)(Wr2 + c * 8000);
        float4* dst4 = (float4*)(&w2s[0][0]);
#pragma unroll
        for (int it = 0; it < 8; ++it) {
            int idx = tid + it * 256;
            if (idx < 2000) dst4[idx] = src4[idx];
        }
        __syncthreads();
#pragma unroll
        for (int t = 0; t < 5; ++t) {
            int ol = sub + 8 * t;            // lane owns output o = c*40 + ol
            int o  = c * 40 + ol;
            float acc = br2[o];
            const float4* wv = (const float4*)(&w2s[ol][0]);
            const float4* hv = (const float4*)(&h1s[g][0]);
#pragma unroll 10
            for (int q = 0; q < 50; ++q) {
                float4 a = wv[q], b = hv[q];
                acc = fmaf(a.x, b.x, acc);
                acc = fmaf(a.y, b.y, acc);
                acc = fmaf(a.z, b.z, acc);
                acc = fmaf(a.w, b.w, acc);
            }
            float h2 = gelu_exact(acc);
            tacc = fmaf(Wr3[o], h2, tacc);
        }
        __syncthreads();
    }

    // t -> T10 -> E -> X_out
    tacc += __shfl_xor(tacc, 1, 8);
    tacc += __shfl_xor(tacc, 2, 8);
    tacc += __shfl_xor(tacc, 4, 8);
    float tval = tacc + br3[0];
    float sig  = __fdividef(1.0f, 1.0f + __expf(-tval));
    float T10  = 0.1f + 6.9f * sig;
    float R1   = 1.0f / T10;
    float E    = __expf(-TRv[row] * R1);

    float xo[4]; float ssum = 0.f;
#pragma unroll
    for (int t = 0; t < 4; ++t) {
        int p = sub + 8 * t;
        float fa = Fin[row * 32 + p];
        float sn = __sinf(fa), cs = __cosf(fa);
        float v = __fdividef((1.0f - E) * sn, 1.0f - cs * E);
        xo[t] = v; ssum += v;
    }
    ssum += __shfl_xor(ssum, 1, 8);
    ssum += __shfl_xor(ssum, 2, 8);
    ssum += __shfl_xor(ssum, 4, 8);
    float mean2 = ssum / (float)fa_len[row];
    float inv   = __fdividef(1.0f, mean2);
#pragma unroll
    for (int t = 0; t < 4; ++t) {
        int p = sub + 8 * t;
        out[row * 32 + p] = xo[t] * inv;
    }
    if (sub == 0) {
        out[B_ROWS * L_SEQ + row] = T10;            // T10
        out[B_ROWS * L_SEQ + B_ROWS + row] = 1.0f;  // M0
    }
}

extern "C" void kernel_launch(void* const* d_in, const int* in_sizes, int n_in,
                              void* d_out, int out_size, void* d_ws, size_t ws_size,
                              hipStream_t stream) {
    const float* Xin  = (const float*)d_in[0];   // X_fa_in  (B,32)
    const float* Fin  = (const float*)d_in[1];   // fa_vals_in (B,32)
    const float* TRv  = (const float*)d_in[2];   // TR_vals (B,1)
    const float* Wi   = (const float*)d_in[3];   // W_init (8,2)
    const float* bi   = (const float*)d_in[4];   // b_init (8)
    const float* W1g  = (const float*)d_in[5];   // W1 (256,8)
    const float* b1g  = (const float*)d_in[6];   // b1 (256)
    const float* W2g  = (const float*)d_in[7];   // W2 (16,256)
    const float* b2g  = (const float*)d_in[8];   // b2 (16)
    const float* Wr1  = (const float*)d_in[9];   // (200,8)
    const float* br1  = (const float*)d_in[10];  // (200)
    const float* Wr2  = (const float*)d_in[11];  // (200,200)
    const float* br2  = (const float*)d_in[12];  // (200)
    const float* Wr3  = (const float*)d_in[13];  // (1,200)
    const float* br3  = (const float*)d_in[14];  // (1)
    // d_in[15] = fa_mask (unused)
    const int*   flen = (const int*)d_in[16];    // fa_len (B,1)

    float* outp = (float*)d_out;
    float* zT   = (float*)d_ws;                  // 16384*8 floats = 512 KB

    ode_kernel<<<dim3(B_ROWS / 16), dim3(256), 0, stream>>>(
        Xin, Fin, flen, Wi, bi, W1g, b1g, W2g, b2g, zT);
    readout_kernel<<<dim3(B_ROWS / 32), dim3(256), 0, stream>>>(
        zT, Fin, TRv, flen, Wr1, br1, Wr2, br2, Wr3, br3, outp);
}

// Round 3
// 1352.222 us; speedup vs baseline: 1.3560x; 1.3560x over previous
//
#include <hip/hip_runtime.h>
#include <hip/hip_bf16.h>

// Problem constants (fixed by the reference)
#define B_ROWS 16384
#define L_SEQ  32

// ---------- fast device math ----------
__device__ __forceinline__ float tanh_fast(float x) {
    float e = __expf(2.0f * x);
    return 1.0f - __fdividef(2.0f, e + 1.0f);
}
__device__ __forceinline__ float gelu_exact(float x) {
    return 0.5f * x * (1.0f + erff(x * 0.70710678118654752440f));
}

// ---------- DPP rotation-reduce across the 16-lane row (VALU pipe, no LDS) ----------
template<int CTRL>
__device__ __forceinline__ float dpp_add_step(float v) {
    int r = __builtin_amdgcn_update_dpp(0, __float_as_int(v), CTRL, 0xf, 0xf, false);
    return v + __int_as_float(r);
}
__device__ __forceinline__ float rotsum16(float v) {
    v = dpp_add_step<0x121>(v);   // row_ror:1
    v = dpp_add_step<0x122>(v);   // row_ror:2
    v = dpp_add_step<0x124>(v);   // row_ror:4
    v = dpp_add_step<0x128>(v);   // row_ror:8
    return v;                     // every lane now holds the 16-lane sum
}

// ---------- F(s, z) for TWO rows sharing one weight read ----------
// Lane `sub` (0..15) owns hidden units j = sub + 16*t. b1 lives in per-lane
// registers (b1v[t] = b1[sub+16t]); b2 is added after the reduction.
__device__ __forceinline__ void Ffunc2(const float* __restrict__ sW1,
                                       const float* __restrict__ sW2T,
                                       int sub,
                                       const float (&zA)[8], const float (&zB)[8],
                                       const float (&b1v)[16], const float (&b2f)[16],
                                       float dA0, float dA1, float dB0, float dB1,
                                       float (&kA)[8], float (&kB)[8])
{
    float GA[16], GB[16];
#pragma unroll
    for (int o = 0; o < 16; ++o) { GA[o] = 0.0f; GB[o] = 0.0f; }

#pragma unroll 4
    for (int t = 0; t < 16; ++t) {
        const int j = sub + (t << 4);
        const float* wr = sW1 + j * 12;             // 48B stride: 2-way alias (free)
        float4 wa = *(const float4*)(wr);
        float4 wb = *(const float4*)(wr + 4);
        float hA = b1v[t], hB = b1v[t];
        hA = fmaf(wa.x, zA[0], hA);  hB = fmaf(wa.x, zB[0], hB);
        hA = fmaf(wa.y, zA[1], hA);  hB = fmaf(wa.y, zB[1], hB);
        hA = fmaf(wa.z, zA[2], hA);  hB = fmaf(wa.z, zB[2], hB);
        hA = fmaf(wa.w, zA[3], hA);  hB = fmaf(wa.w, zB[3], hB);
        hA = fmaf(wb.x, zA[4], hA);  hB = fmaf(wb.x, zB[4], hB);
        hA = fmaf(wb.y, zA[5], hA);  hB = fmaf(wb.y, zB[5], hB);
        hA = fmaf(wb.z, zA[6], hA);  hB = fmaf(wb.z, zB[6], hB);
        hA = fmaf(wb.w, zA[7], hA);  hB = fmaf(wb.w, zB[7], hB);
        hA = fmaxf(hA, 0.0f);        hB = fmaxf(hB, 0.0f);

        const float* vr = sW2T + j * 20;            // 80B stride: 2-way alias (free)
        float4 v0 = *(const float4*)(vr);
        float4 v1 = *(const float4*)(vr + 4);
        float4 v2 = *(const float4*)(vr + 8);
        float4 v3 = *(const float4*)(vr + 12);
        GA[0]  = fmaf(v0.x, hA, GA[0]);   GB[0]  = fmaf(v0.x, hB, GB[0]);
        GA[1]  = fmaf(v0.y, hA, GA[1]);   GB[1]  = fmaf(v0.y, hB, GB[1]);
        GA[2]  = fmaf(v0.z, hA, GA[2]);   GB[2]  = fmaf(v0.z, hB, GB[2]);
        GA[3]  = fmaf(v0.w, hA, GA[3]);   GB[3]  = fmaf(v0.w, hB, GB[3]);
        GA[4]  = fmaf(v1.x, hA, GA[4]);   GB[4]  = fmaf(v1.x, hB, GB[4]);
        GA[5]  = fmaf(v1.y, hA, GA[5]);   GB[5]  = fmaf(v1.y, hB, GB[5]);
        GA[6]  = fmaf(v1.z, hA, GA[6]);   GB[6]  = fmaf(v1.z, hB, GB[6]);
        GA[7]  = fmaf(v1.w, hA, GA[7]);   GB[7]  = fmaf(v1.w, hB, GB[7]);
        GA[8]  = fmaf(v2.x, hA, GA[8]);   GB[8]  = fmaf(v2.x, hB, GB[8]);
        GA[9]  = fmaf(v2.y, hA, GA[9]);   GB[9]  = fmaf(v2.y, hB, GB[9]);
        GA[10] = fmaf(v2.z, hA, GA[10]);  GB[10] = fmaf(v2.z, hB, GB[10]);
        GA[11] = fmaf(v2.w, hA, GA[11]);  GB[11] = fmaf(v2.w, hB, GB[11]);
        GA[12] = fmaf(v3.x, hA, GA[12]);  GB[12] = fmaf(v3.x, hB, GB[12]);
        GA[13] = fmaf(v3.y, hA, GA[13]);  GB[13] = fmaf(v3.y, hB, GB[13]);
        GA[14] = fmaf(v3.z, hA, GA[14]);  GB[14] = fmaf(v3.z, hB, GB[14]);
        GA[15] = fmaf(v3.w, hA, GA[15]);  GB[15] = fmaf(v3.w, hB, GB[15]);
    }

    // DPP reduction: 0 DS instructions
#pragma unroll
    for (int o = 0; o < 16; ++o) { GA[o] = rotsum16(GA[o]); GB[o] = rotsum16(GB[o]); }

#pragma unroll
    for (int hh = 0; hh < 8; ++hh) {
        float gaA = tanh_fast(GA[2 * hh]     + b2f[2 * hh]);
        float gbA = tanh_fast(GA[2 * hh + 1] + b2f[2 * hh + 1]);
        float gaB = tanh_fast(GB[2 * hh]     + b2f[2 * hh]);
        float gbB = tanh_fast(GB[2 * hh + 1] + b2f[2 * hh + 1]);
        kA[hh] = fmaf(gaA, dA0, gbA * dA1);
        kB[hh] = fmaf(gaB, dB0, gbB * dB1);
    }
}

// ---------- Kernel 1: preprocessing + RK4 neural-ODE integration ----------
// 16-lane group handles 2 rows; 32 rows per 256-thread block.
__global__ __launch_bounds__(256) void ode_kernel(
    const float* __restrict__ Xin, const float* __restrict__ Fin,
    const int*   __restrict__ fa_len,
    const float* __restrict__ Wi,  const float* __restrict__ bi,
    const float* __restrict__ W1g, const float* __restrict__ b1g,
    const float* __restrict__ W2g, const float* __restrict__ b2g,
    float* __restrict__ zT)
{
    __shared__ float sW1[256 * 12];     // [w0..w7, pad, pad, pad, pad]
    __shared__ float sW2T[256 * 20];    // W2 transposed, padded 16->20
    __shared__ float xm[32][32][4];     // per row: {fa, X, m_fa, m_X}

    const int tid = threadIdx.x;

    // stage weights (thread t handles hidden unit t)
    {
        const float* w = W1g + tid * 8;
        float* d = sW1 + tid * 12;
        *(float4*)(d)     = *(const float4*)(w);
        *(float4*)(d + 4) = *(const float4*)(w + 4);
#pragma unroll
        for (int o = 0; o < 16; ++o) sW2T[tid * 20 + o] = W2g[o * 256 + tid];
    }

    const int g16 = tid >> 4;           // group 0..15
    const int sub = tid & 15;

    // per-lane b1 slice; broadcast b2
    float b1v[16], b2f[16];
#pragma unroll
    for (int t = 0; t < 16; ++t) b1v[t] = b1g[sub + (t << 4)];
#pragma unroll
    for (int o = 0; o < 16; ++o) b2f[o] = b2g[o];

    // ---- preprocessing for the group's 2 rows ----
    float mean_r[2]; int fl_r[2];
#pragma unroll
    for (int r = 0; r < 2; ++r) {
        const int row_l = g16 * 2 + r;
        const int row   = blockIdx.x * 32 + row_l;
        const float* Xr = Xin + row * L_SEQ;
        const float* Fr = Fin + row * L_SEQ;
        float xr0 = Xr[sub], xr1 = Xr[sub + 16];
        float fr0 = Fr[sub], fr1 = Fr[sub + 16];
        fl_r[r] = fa_len[row];

        float s = xr0 + xr1;
        s += __shfl_xor(s, 1, 16);
        s += __shfl_xor(s, 2, 16);
        s += __shfl_xor(s, 4, 16);
        s += __shfl_xor(s, 8, 16);
        mean_r[r] = s / (float)fl_r[r];

        xm[row_l][sub][0]      = fr0; xm[row_l][sub][1]      = xr0;
        xm[row_l][sub + 16][0] = fr1; xm[row_l][sub + 16][1] = xr1;
    }
    __syncthreads();

    float ff[2][2], xf[2][2];
#pragma unroll
    for (int r = 0; r < 2; ++r) {
        const int row_l = g16 * 2 + r;
        const int fl = fl_r[r];
        const float mean = mean_r[r];
        const int shift = L_SEQ - fl;
        int lsrc  = fl - 1 - shift;
        int lsrcC = lsrc < 0 ? 0 : lsrc;
        float lastX = (lsrc >= 0) ? (xm[row_l][lsrcC][1] / mean) : 0.0f;
        float lastF = xm[row_l][fl - 1][0];
#pragma unroll
        for (int u = 0; u < 2; ++u) {
            int p = sub + u * 16;
            int src = p - shift;
            int sc  = src < 0 ? 0 : src;
            float fraw = xm[row_l][sc][0];
            float xraw = xm[row_l][sc][1];
            ff[r][u] = (src >= 0) ? fraw : lastF;
            xf[r][u] = (src >= 0) ? (xraw / mean) : lastX;
        }
    }
    __syncthreads();
#pragma unroll
    for (int r = 0; r < 2; ++r) {
        const int row_l = g16 * 2 + r;
#pragma unroll
        for (int u = 0; u < 2; ++u) {
            int p = sub + u * 16;
            xm[row_l][p][0] = ff[r][u];
            xm[row_l][p][1] = xf[r][u];
        }
    }
    __syncthreads();
#pragma unroll
    for (int r = 0; r < 2; ++r) {
        const int row_l = g16 * 2 + r;
#pragma unroll
        for (int u = 0; u < 2; ++u) {
            int p = sub + u * 16;
            int q = (p == 0) ? 1 : p;          // m[0] = x[1]-x[0]
            float mf = xm[row_l][q][0] - xm[row_l][q - 1][0];
            float mX = xm[row_l][q][1] - xm[row_l][q - 1][1];
            xm[row_l][p][2] = mf;
            xm[row_l][p][3] = mX;
        }
    }
    __syncthreads();

    // z0 for both rows (replicated across the group's 16 lanes)
    const int lA = g16 * 2, lB = g16 * 2 + 1;
    float zA[8], zB[8];
    {
        float fA = xm[lA][0][0], XA = xm[lA][0][1];
        float fB = xm[lB][0][0], XB = xm[lB][0][1];
#pragma unroll
        for (int h = 0; h < 8; ++h) {
            zA[h] = fmaf(Wi[h * 2], fA, fmaf(Wi[h * 2 + 1], XA, bi[h]));
            zB[h] = fmaf(Wi[h * 2], fB, fmaf(Wi[h * 2 + 1], XB, bi[h]));
        }
    }

    // ---- 31 intervals x 2 substeps of RK4 ----
#pragma unroll 1
    for (int i = 0; i < 31; ++i) {
        float4 A0 = *(const float4*)(&xm[lA][i][0]);
        float4 A1 = *(const float4*)(&xm[lA][i + 1][0]);
        float4 B0 = *(const float4*)(&xm[lB][i][0]);
        float4 B1 = *(const float4*)(&xm[lB][i + 1][0]);

        // d(s) = c0*(x0-x1) + c1*m0 + c3*m1, channel 0 = fa, 1 = X
        float m0A0 = A0.z, m0A1 = A0.w, m1A0 = A1.z, m1A1 = A1.w;
        float m0B0 = B0.z, m0B1 = B0.w, m1B0 = B1.z, m1B1 = B1.w;
        float dAf = A0.x - A1.x, dAX = A0.y - A1.y;
        float dBf = B0.x - B1.x, dBX = B0.y - B1.y;

        float d25A0 = fmaf(-1.125f, dAf, fmaf(0.1875f, m0A0, -0.3125f * m1A0));
        float d25A1 = fmaf(-1.125f, dAX, fmaf(0.1875f, m0A1, -0.3125f * m1A1));
        float d25B0 = fmaf(-1.125f, dBf, fmaf(0.1875f, m0B0, -0.3125f * m1B0));
        float d25B1 = fmaf(-1.125f, dBX, fmaf(0.1875f, m0B1, -0.3125f * m1B1));

        float d50A0 = fmaf(-1.5f, dAf, fmaf(-0.25f, m0A0, -0.25f * m1A0));
        float d50A1 = fmaf(-1.5f, dAX, fmaf(-0.25f, m0A1, -0.25f * m1A1));
        float d50B0 = fmaf(-1.5f, dBf, fmaf(-0.25f, m0B0, -0.25f * m1B0));
        float d50B1 = fmaf(-1.5f, dBX, fmaf(-0.25f, m0B1, -0.25f * m1B1));

        float d75A0 = fmaf(-1.125f, dAf, fmaf(-0.3125f, m0A0, 0.1875f * m1A0));
        float d75A1 = fmaf(-1.125f, dAX, fmaf(-0.3125f, m0A1, 0.1875f * m1A1));
        float d75B0 = fmaf(-1.125f, dBf, fmaf(-0.3125f, m0B0, 0.1875f * m1B0));
        float d75B1 = fmaf(-1.125f, dBX, fmaf(-0.3125f, m0B1, 0.1875f * m1B1));

#pragma unroll 1
        for (int ssi = 0; ssi < 2; ++ssi) {
            float daA0 = ssi ? d50A0 : m0A0,  daA1 = ssi ? d50A1 : m0A1;
            float daB0 = ssi ? d50B0 : m0B0,  daB1 = ssi ? d50B1 : m0B1;
            float dbA0 = ssi ? d75A0 : d25A0, dbA1 = ssi ? d75A1 : d25A1;
            float dbB0 = ssi ? d75B0 : d25B0, dbB1 = ssi ? d75B1 : d25B1;
            float ddA0 = ssi ? m1A0 : d50A0,  ddA1 = ssi ? m1A1 : d50A1;
            float ddB0 = ssi ? m1B0 : d50B0,  ddB1 = ssi ? m1B1 : d50B1;

            float kA[8], kB[8], kaccA[8], kaccB[8], zzA[8], zzB[8];
            Ffunc2(sW1, sW2T, sub, zA, zB, b1v, b2f, daA0, daA1, daB0, daB1, kA, kB);   // k1
#pragma unroll
            for (int h = 0; h < 8; ++h) {
                kaccA[h] = kA[h];                    zzA[h] = fmaf(0.25f, kA[h], zA[h]);
                kaccB[h] = kB[h];                    zzB[h] = fmaf(0.25f, kB[h], zB[h]);
            }
            Ffunc2(sW1, sW2T, sub, zzA, zzB, b1v, b2f, dbA0, dbA1, dbB0, dbB1, kA, kB); // k2
#pragma unroll
            for (int h = 0; h < 8; ++h) {
                kaccA[h] = fmaf(2.0f, kA[h], kaccA[h]); zzA[h] = fmaf(0.25f, kA[h], zA[h]);
                kaccB[h] = fmaf(2.0f, kB[h], kaccB[h]); zzB[h] = fmaf(0.25f, kB[h], zB[h]);
            }
            Ffunc2(sW1, sW2T, sub, zzA, zzB, b1v, b2f, dbA0, dbA1, dbB0, dbB1, kA, kB); // k3
#pragma unroll
            for (int h = 0; h < 8; ++h) {
                kaccA[h] = fmaf(2.0f, kA[h], kaccA[h]); zzA[h] = fmaf(0.5f, kA[h], zA[h]);
                kaccB[h] = fmaf(2.0f, kB[h], kaccB[h]); zzB[h] = fmaf(0.5f, kB[h], zB[h]);
            }
            Ffunc2(sW1, sW2T, sub, zzA, zzB, b1v, b2f, ddA0, ddA1, ddB0, ddB1, kA, kB); // k4
#pragma unroll
            for (int h = 0; h < 8; ++h) {
                zA[h] = fmaf(1.0f / 12.0f, kaccA[h] + kA[h], zA[h]);
                zB[h] = fmaf(1.0f / 12.0f, kaccB[h] + kB[h], zB[h]);
            }
        }
    }

    if (sub == 0) {
        const int rowA = blockIdx.x * 32 + lA;
        float4* dstA = (float4*)(zT + rowA * 8);
        dstA[0] = make_float4(zA[0], zA[1], zA[2], zA[3]);
        dstA[1] = make_float4(zA[4], zA[5], zA[6], zA[7]);
        float4* dstB = (float4*)(zT + (rowA + 1) * 8);
        dstB[0] = make_float4(zB[0], zB[1], zB[2], zB[3]);
        dstB[1] = make_float4(zB[4], zB[5], zB[6], zB[7]);
    }
}

// ---------- Kernel 2: gelu readout + T10 + X_out ----------
__global__ __launch_bounds__(256) void readout_kernel(
    const float* __restrict__ zT,
    const float* __restrict__ Fin,
    const float* __restrict__ TRv,
    const int*   __restrict__ fa_len,
    const float* __restrict__ Wr1, const float* __restrict__ br1,
    const float* __restrict__ Wr2, const float* __restrict__ br2,
    const float* __restrict__ Wr3, const float* __restrict__ br3,
    float* __restrict__ out)
{
    __shared__ float h1s[32][200];     // per-row h1
    __shared__ float w2s[40][200];     // Wr2 chunk (5 chunks of 40 rows)
    const int tid = threadIdx.x;
    const int g = tid >> 3, sub = tid & 7;
    const int row = blockIdx.x * 32 + g;

    float4 za = *(const float4*)(zT + row * 8);
    float4 zb = *(const float4*)(zT + row * 8 + 4);

#pragma unroll 5
    for (int t = 0; t < 25; ++t) {
        int j = sub + 8 * t;
        const float* w = Wr1 + j * 8;
        float4 wa = *(const float4*)(w);
        float4 wb = *(const float4*)(w + 4);
        float acc = br1[j];
        acc = fmaf(wa.x, za.x, acc);
        acc = fmaf(wa.y, za.y, acc);
        acc = fmaf(wa.z, za.z, acc);
        acc = fmaf(wa.w, za.w, acc);
        acc = fmaf(wb.x, zb.x, acc);
        acc = fmaf(wb.y, zb.y, acc);
        acc = fmaf(wb.z, zb.z, acc);
        acc = fmaf(wb.w, zb.w, acc);
        h1s[g][j] = gelu_exact(acc);
    }
    __syncthreads();

    float tacc = 0.0f;
    for (int c = 0; c < 5; ++c) {
        const float4* src4 = (const float4*)(Wr2 + c * 8000);
        float4* dst4 = (float4*)(&w2s[0][0]);
#pragma unroll
        for (int it = 0; it < 8; ++it) {
            int idx = tid + it * 256;
            if (idx < 2000) dst4[idx] = src4[idx];
        }
        __syncthreads();
#pragma unroll
        for (int t = 0; t < 5; ++t) {
            int ol = sub + 8 * t;
            int o  = c * 40 + ol;
            float acc = br2[o];
            const float4* wv = (const float4*)(&w2s[ol][0]);
            const float4* hv = (const float4*)(&h1s[g][0]);
#pragma unroll 10
            for (int q = 0; q < 50; ++q) {
                float4 a = wv[q], b = hv[q];
                acc = fmaf(a.x, b.x, acc);
                acc = fmaf(a.y, b.y, acc);
                acc = fmaf(a.z, b.z, acc);
                acc = fmaf(a.w, b.w, acc);
            }
            float h2 = gelu_exact(acc);
            tacc = fmaf(Wr3[o], h2, tacc);
        }
        __syncthreads();
    }

    tacc += __shfl_xor(tacc, 1, 8);
    tacc += __shfl_xor(tacc, 2, 8);
    tacc += __shfl_xor(tacc, 4, 8);
    float tval = tacc + br3[0];
    float sig  = __fdividef(1.0f, 1.0f + __expf(-tval));
    float T10  = 0.1f + 6.9f * sig;
    float R1   = 1.0f / T10;
    float E    = __expf(-TRv[row] * R1);

    float xo[4]; float ssum = 0.f;
#pragma unroll
    for (int t = 0; t < 4; ++t) {
        int p = sub + 8 * t;
        float fa = Fin[row * 32 + p];
        float sn = __sinf(fa), cs = __cosf(fa);
        float v = __fdividef((1.0f - E) * sn, 1.0f - cs * E);
        xo[t] = v; ssum += v;
    }
    ssum += __shfl_xor(ssum, 1, 8);
    ssum += __shfl_xor(ssum, 2, 8);
    ssum += __shfl_xor(ssum, 4, 8);
    float mean2 = ssum / (float)fa_len[row];
    float inv   = __fdividef(1.0f, mean2);
#pragma unroll
    for (int t = 0; t < 4; ++t) {
        int p = sub + 8 * t;
        out[row * 32 + p] = xo[t] * inv;
    }
    if (sub == 0) {
        out[B_ROWS * L_SEQ + row] = T10;
        out[B_ROWS * L_SEQ + B_ROWS + row] = 1.0f;
    }
}

extern "C" void kernel_launch(void* const* d_in, const int* in_sizes, int n_in,
                              void* d_out, int out_size, void* d_ws, size_t ws_size,
                              hipStream_t stream) {
    const float* Xin  = (const float*)d_in[0];
    const float* Fin  = (const float*)d_in[1];
    const float* TRv  = (const float*)d_in[2];
    const float* Wi   = (const float*)d_in[3];
    const float* bi   = (const float*)d_in[4];
    const float* W1g  = (const float*)d_in[5];
    const float* b1g  = (const float*)d_in[6];
    const float* W2g  = (const float*)d_in[7];
    const float* b2g  = (const float*)d_in[8];
    const float* Wr1  = (const float*)d_in[9];
    const float* br1  = (const float*)d_in[10];
    const float* Wr2  = (const float*)d_in[11];
    const float* br2  = (const float*)d_in[12];
    const float* Wr3  = (const float*)d_in[13];
    const float* br3  = (const float*)d_in[14];
    const int*   flen = (const int*)d_in[16];

    float* outp = (float*)d_out;
    float* zT   = (float*)d_ws;

    ode_kernel<<<dim3(B_ROWS / 32), dim3(256), 0, stream>>>(
        Xin, Fin, flen, Wi, bi, W1g, b1g, W2g, b2g, zT);
    readout_kernel<<<dim3(B_ROWS / 32), dim3(256), 0, stream>>>(
        zT, Fin, TRv, flen, Wr1, br1, Wr2, br2, Wr3, br3, outp);
}

// Round 4
// 1148.522 us; speedup vs baseline: 1.5965x; 1.1774x over previous
//
#include <hip/hip_runtime.h>
#include <hip/hip_bf16.h>

// Problem constants (fixed by the reference)
#define B_ROWS 16384
#define L_SEQ  32

// ---------- fast device math ----------
__device__ __forceinline__ float tanh_fast(float x) {
    // tanh(x) = 1 - 2/(e^{2x}+1); 6 VALU slots: mul, mul(log2e), v_exp, add, rcp, fma
    float e = __expf(2.0f * x);
    float r = __builtin_amdgcn_rcpf(e + 1.0f);
    return fmaf(-2.0f, r, 1.0f);
}
__device__ __forceinline__ float gelu_exact(float x) {
    return 0.5f * x * (1.0f + erff(x * 0.70710678118654752440f));
}

// ---------- fused DPP rotation-reduce across the 16-lane row (1 instr/step) ----------
// v_add_f32_dpp dst, src0(dpp row_ror:N), src1 : dst = rotated(src) + src
__device__ __forceinline__ float rotsum16(float v) {
    float t0, t1, t2, t3;
    asm("v_add_f32_dpp %0, %1, %1 row_ror:1 row_mask:0xf bank_mask:0xf"
        : "=v"(t0) : "v"(v));
    asm("v_add_f32_dpp %0, %1, %1 row_ror:2 row_mask:0xf bank_mask:0xf"
        : "=v"(t1) : "v"(t0));
    asm("v_add_f32_dpp %0, %1, %1 row_ror:4 row_mask:0xf bank_mask:0xf"
        : "=v"(t2) : "v"(t1));
    asm("v_add_f32_dpp %0, %1, %1 row_ror:8 row_mask:0xf bank_mask:0xf"
        : "=v"(t3) : "v"(t2));
    return t3;                    // every lane now holds the 16-lane sum
}

// ---------- F(s, z) for TWO rows sharing one weight read ----------
// Lane `sub` (0..15) owns hidden units j = sub + 16*t. b1 lives in per-lane
// registers (b1v[t]); b2/16 seeds the accumulators (reduction sums it exactly).
__device__ __forceinline__ void Ffunc2(const float* __restrict__ sW1,
                                       const float* __restrict__ sW2T,
                                       int sub,
                                       const float (&zA)[8], const float (&zB)[8],
                                       const float (&b1v)[16], const float (&b2s)[16],
                                       float dA0, float dA1, float dB0, float dB1,
                                       float (&kA)[8], float (&kB)[8])
{
    float GA[16], GB[16];
#pragma unroll
    for (int o = 0; o < 16; ++o) { GA[o] = b2s[o]; GB[o] = b2s[o]; }

#pragma unroll 4
    for (int t = 0; t < 16; ++t) {
        const int j = sub + (t << 4);
        const float* wr = sW1 + j * 12;             // 48B stride: 2-way alias (free)
        float4 wa = *(const float4*)(wr);
        float4 wb = *(const float4*)(wr + 4);
        float hA = b1v[t], hB = b1v[t];
        hA = fmaf(wa.x, zA[0], hA);  hB = fmaf(wa.x, zB[0], hB);
        hA = fmaf(wa.y, zA[1], hA);  hB = fmaf(wa.y, zB[1], hB);
        hA = fmaf(wa.z, zA[2], hA);  hB = fmaf(wa.z, zB[2], hB);
        hA = fmaf(wa.w, zA[3], hA);  hB = fmaf(wa.w, zB[3], hB);
        hA = fmaf(wb.x, zA[4], hA);  hB = fmaf(wb.x, zB[4], hB);
        hA = fmaf(wb.y, zA[5], hA);  hB = fmaf(wb.y, zB[5], hB);
        hA = fmaf(wb.z, zA[6], hA);  hB = fmaf(wb.z, zB[6], hB);
        hA = fmaf(wb.w, zA[7], hA);  hB = fmaf(wb.w, zB[7], hB);
        hA = fmaxf(hA, 0.0f);        hB = fmaxf(hB, 0.0f);

        const float* vr = sW2T + j * 20;            // 80B stride: 2-way alias (free)
        float4 v0 = *(const float4*)(vr);
        float4 v1 = *(const float4*)(vr + 4);
        float4 v2 = *(const float4*)(vr + 8);
        float4 v3 = *(const float4*)(vr + 12);
        GA[0]  = fmaf(v0.x, hA, GA[0]);   GB[0]  = fmaf(v0.x, hB, GB[0]);
        GA[1]  = fmaf(v0.y, hA, GA[1]);   GB[1]  = fmaf(v0.y, hB, GB[1]);
        GA[2]  = fmaf(v0.z, hA, GA[2]);   GB[2]  = fmaf(v0.z, hB, GB[2]);
        GA[3]  = fmaf(v0.w, hA, GA[3]);   GB[3]  = fmaf(v0.w, hB, GB[3]);
        GA[4]  = fmaf(v1.x, hA, GA[4]);   GB[4]  = fmaf(v1.x, hB, GB[4]);
        GA[5]  = fmaf(v1.y, hA, GA[5]);   GB[5]  = fmaf(v1.y, hB, GB[5]);
        GA[6]  = fmaf(v1.z, hA, GA[6]);   GB[6]  = fmaf(v1.z, hB, GB[6]);
        GA[7]  = fmaf(v1.w, hA, GA[7]);   GB[7]  = fmaf(v1.w, hB, GB[7]);
        GA[8]  = fmaf(v2.x, hA, GA[8]);   GB[8]  = fmaf(v2.x, hB, GB[8]);
        GA[9]  = fmaf(v2.y, hA, GA[9]);   GB[9]  = fmaf(v2.y, hB, GB[9]);
        GA[10] = fmaf(v2.z, hA, GA[10]);  GB[10] = fmaf(v2.z, hB, GB[10]);
        GA[11] = fmaf(v2.w, hA, GA[11]);  GB[11] = fmaf(v2.w, hB, GB[11]);
        GA[12] = fmaf(v3.x, hA, GA[12]);  GB[12] = fmaf(v3.x, hB, GB[12]);
        GA[13] = fmaf(v3.y, hA, GA[13]);  GB[13] = fmaf(v3.y, hB, GB[13]);
        GA[14] = fmaf(v3.z, hA, GA[14]);  GB[14] = fmaf(v3.z, hB, GB[14]);
        GA[15] = fmaf(v3.w, hA, GA[15]);  GB[15] = fmaf(v3.w, hB, GB[15]);
    }

    // fused-DPP reduction: 4 instr per value, 0 DS instructions
#pragma unroll
    for (int o = 0; o < 16; ++o) { GA[o] = rotsum16(GA[o]); GB[o] = rotsum16(GB[o]); }

#pragma unroll
    for (int hh = 0; hh < 8; ++hh) {
        float gaA = tanh_fast(GA[2 * hh]);
        float gbA = tanh_fast(GA[2 * hh + 1]);
        float gaB = tanh_fast(GB[2 * hh]);
        float gbB = tanh_fast(GB[2 * hh + 1]);
        kA[hh] = fmaf(gaA, dA0, gbA * dA1);
        kB[hh] = fmaf(gaB, dB0, gbB * dB1);
    }
}

// ---------- Kernel 1: preprocessing + RK4 neural-ODE integration ----------
// 16-lane group handles 2 rows; 32 rows per 256-thread block.
__global__ __launch_bounds__(256) void ode_kernel(
    const float* __restrict__ Xin, const float* __restrict__ Fin,
    const int*   __restrict__ fa_len,
    const float* __restrict__ Wi,  const float* __restrict__ bi,
    const float* __restrict__ W1g, const float* __restrict__ b1g,
    const float* __restrict__ W2g, const float* __restrict__ b2g,
    float* __restrict__ zT)
{
    __shared__ float sW1[256 * 12];     // [w0..w7, pad, pad, pad, pad]
    __shared__ float sW2T[256 * 20];    // W2 transposed, padded 16->20
    __shared__ float xm[32][32][4];     // per row: {fa, X, m_fa, m_X}

    const int tid = threadIdx.x;

    // stage weights (thread t handles hidden unit t)
    {
        const float* w = W1g + tid * 8;
        float* d = sW1 + tid * 12;
        *(float4*)(d)     = *(const float4*)(w);
        *(float4*)(d + 4) = *(const float4*)(w + 4);
#pragma unroll
        for (int o = 0; o < 16; ++o) sW2T[tid * 20 + o] = W2g[o * 256 + tid];
    }

    const int g16 = tid >> 4;           // group 0..15
    const int sub = tid & 15;

    // per-lane b1 slice; b2 pre-scaled by 1/16 (reduction over 16 lanes restores it)
    float b1v[16], b2s[16];
#pragma unroll
    for (int t = 0; t < 16; ++t) b1v[t] = b1g[sub + (t << 4)];
#pragma unroll
    for (int o = 0; o < 16; ++o) b2s[o] = b2g[o] * 0.0625f;

    // ---- preprocessing for the group's 2 rows ----
    float mean_r[2]; int fl_r[2];
#pragma unroll
    for (int r = 0; r < 2; ++r) {
        const int row_l = g16 * 2 + r;
        const int row   = blockIdx.x * 32 + row_l;
        const float* Xr = Xin + row * L_SEQ;
        const float* Fr = Fin + row * L_SEQ;
        float xr0 = Xr[sub], xr1 = Xr[sub + 16];
        float fr0 = Fr[sub], fr1 = Fr[sub + 16];
        fl_r[r] = fa_len[row];

        float s = xr0 + xr1;
        s += __shfl_xor(s, 1, 16);
        s += __shfl_xor(s, 2, 16);
        s += __shfl_xor(s, 4, 16);
        s += __shfl_xor(s, 8, 16);
        mean_r[r] = s / (float)fl_r[r];

        xm[row_l][sub][0]      = fr0; xm[row_l][sub][1]      = xr0;
        xm[row_l][sub + 16][0] = fr1; xm[row_l][sub + 16][1] = xr1;
    }
    __syncthreads();

    float ff[2][2], xf[2][2];
#pragma unroll
    for (int r = 0; r < 2; ++r) {
        const int row_l = g16 * 2 + r;
        const int fl = fl_r[r];
        const float mean = mean_r[r];
        const int shift = L_SEQ - fl;
        int lsrc  = fl - 1 - shift;
        int lsrcC = lsrc < 0 ? 0 : lsrc;
        float lastX = (lsrc >= 0) ? (xm[row_l][lsrcC][1] / mean) : 0.0f;
        float lastF = xm[row_l][fl - 1][0];
#pragma unroll
        for (int u = 0; u < 2; ++u) {
            int p = sub + u * 16;
            int src = p - shift;
            int sc  = src < 0 ? 0 : src;
            float fraw = xm[row_l][sc][0];
            float xraw = xm[row_l][sc][1];
            ff[r][u] = (src >= 0) ? fraw : lastF;
            xf[r][u] = (src >= 0) ? (xraw / mean) : lastX;
        }
    }
    __syncthreads();
#pragma unroll
    for (int r = 0; r < 2; ++r) {
        const int row_l = g16 * 2 + r;
#pragma unroll
        for (int u = 0; u < 2; ++u) {
            int p = sub + u * 16;
            xm[row_l][p][0] = ff[r][u];
            xm[row_l][p][1] = xf[r][u];
        }
    }
    __syncthreads();
#pragma unroll
    for (int r = 0; r < 2; ++r) {
        const int row_l = g16 * 2 + r;
#pragma unroll
        for (int u = 0; u < 2; ++u) {
            int p = sub + u * 16;
            int q = (p == 0) ? 1 : p;          // m[0] = x[1]-x[0]
            float mf = xm[row_l][q][0] - xm[row_l][q - 1][0];
            float mX = xm[row_l][q][1] - xm[row_l][q - 1][1];
            xm[row_l][p][2] = mf;
            xm[row_l][p][3] = mX;
        }
    }
    __syncthreads();

    // z0 for both rows (replicated across the group's 16 lanes)
    const int lA = g16 * 2, lB = g16 * 2 + 1;
    float zA[8], zB[8];
    {
        float fA = xm[lA][0][0], XA = xm[lA][0][1];
        float fB = xm[lB][0][0], XB = xm[lB][0][1];
#pragma unroll
        for (int h = 0; h < 8; ++h) {
            zA[h] = fmaf(Wi[h * 2], fA, fmaf(Wi[h * 2 + 1], XA, bi[h]));
            zB[h] = fmaf(Wi[h * 2], fB, fmaf(Wi[h * 2 + 1], XB, bi[h]));
        }
    }

    // ---- 31 intervals x 2 substeps of RK4 ----
#pragma unroll 1
    for (int i = 0; i < 31; ++i) {
        float4 A0 = *(const float4*)(&xm[lA][i][0]);
        float4 A1 = *(const float4*)(&xm[lA][i + 1][0]);
        float4 B0 = *(const float4*)(&xm[lB][i][0]);
        float4 B1 = *(const float4*)(&xm[lB][i + 1][0]);

        // d(s) = c0*(x0-x1) + c1*m0 + c3*m1, channel 0 = fa, 1 = X
        float m0A0 = A0.z, m0A1 = A0.w, m1A0 = A1.z, m1A1 = A1.w;
        float m0B0 = B0.z, m0B1 = B0.w, m1B0 = B1.z, m1B1 = B1.w;
        float dAf = A0.x - A1.x, dAX = A0.y - A1.y;
        float dBf = B0.x - B1.x, dBX = B0.y - B1.y;

        float d25A0 = fmaf(-1.125f, dAf, fmaf(0.1875f, m0A0, -0.3125f * m1A0));
        float d25A1 = fmaf(-1.125f, dAX, fmaf(0.1875f, m0A1, -0.3125f * m1A1));
        float d25B0 = fmaf(-1.125f, dBf, fmaf(0.1875f, m0B0, -0.3125f * m1B0));
        float d25B1 = fmaf(-1.125f, dBX, fmaf(0.1875f, m0B1, -0.3125f * m1B1));

        float d50A0 = fmaf(-1.5f, dAf, fmaf(-0.25f, m0A0, -0.25f * m1A0));
        float d50A1 = fmaf(-1.5f, dAX, fmaf(-0.25f, m0A1, -0.25f * m1A1));
        float d50B0 = fmaf(-1.5f, dBf, fmaf(-0.25f, m0B0, -0.25f * m1B0));
        float d50B1 = fmaf(-1.5f, dBX, fmaf(-0.25f, m0B1, -0.25f * m1B1));

        float d75A0 = fmaf(-1.125f, dAf, fmaf(-0.3125f, m0A0, 0.1875f * m1A0));
        float d75A1 = fmaf(-1.125f, dAX, fmaf(-0.3125f, m0A1, 0.1875f * m1A1));
        float d75B0 = fmaf(-1.125f, dBf, fmaf(-0.3125f, m0B0, 0.1875f * m1B0));
        float d75B1 = fmaf(-1.125f, dBX, fmaf(-0.3125f, m0B1, 0.1875f * m1B1));

#pragma unroll 1
        for (int ssi = 0; ssi < 2; ++ssi) {
            float daA0 = ssi ? d50A0 : m0A0,  daA1 = ssi ? d50A1 : m0A1;
            float daB0 = ssi ? d50B0 : m0B0,  daB1 = ssi ? d50B1 : m0B1;
            float dbA0 = ssi ? d75A0 : d25A0, dbA1 = ssi ? d75A1 : d25A1;
            float dbB0 = ssi ? d75B0 : d25B0, dbB1 = ssi ? d75B1 : d25B1;
            float ddA0 = ssi ? m1A0 : d50A0,  ddA1 = ssi ? m1A1 : d50A1;
            float ddB0 = ssi ? m1B0 : d50B0,  ddB1 = ssi ? m1B1 : d50B1;

            float kA[8], kB[8], kaccA[8], kaccB[8], zzA[8], zzB[8];
            Ffunc2(sW1, sW2T, sub, zA, zB, b1v, b2s, daA0, daA1, daB0, daB1, kA, kB);   // k1
#pragma unroll
            for (int h = 0; h < 8; ++h) {
                kaccA[h] = kA[h];                    zzA[h] = fmaf(0.25f, kA[h], zA[h]);
                kaccB[h] = kB[h];                    zzB[h] = fmaf(0.25f, kB[h], zB[h]);
            }
            Ffunc2(sW1, sW2T, sub, zzA, zzB, b1v, b2s, dbA0, dbA1, dbB0, dbB1, kA, kB); // k2
#pragma unroll
            for (int h = 0; h < 8; ++h) {
                kaccA[h] = fmaf(2.0f, kA[h], kaccA[h]); zzA[h] = fmaf(0.25f, kA[h], zA[h]);
                kaccB[h] = fmaf(2.0f, kB[h], kaccB[h]); zzB[h] = fmaf(0.25f, kB[h], zB[h]);
            }
            Ffunc2(sW1, sW2T, sub, zzA, zzB, b1v, b2s, dbA0, dbA1, dbB0, dbB1, kA, kB); // k3
#pragma unroll
            for (int h = 0; h < 8; ++h) {
                kaccA[h] = fmaf(2.0f, kA[h], kaccA[h]); zzA[h] = fmaf(0.5f, kA[h], zA[h]);
                kaccB[h] = fmaf(2.0f, kB[h], kaccB[h]); zzB[h] = fmaf(0.5f, kB[h], zB[h]);
            }
            Ffunc2(sW1, sW2T, sub, zzA, zzB, b1v, b2s, ddA0, ddA1, ddB0, ddB1, kA, kB); // k4
#pragma unroll
            for (int h = 0; h < 8; ++h) {
                zA[h] = fmaf(1.0f / 12.0f, kaccA[h] + kA[h], zA[h]);
                zB[h] = fmaf(1.0f / 12.0f, kaccB[h] + kB[h], zB[h]);
            }
        }
    }

    if (sub == 0) {
        const int rowA = blockIdx.x * 32 + lA;
        float4* dstA = (float4*)(zT + rowA * 8);
        dstA[0] = make_float4(zA[0], zA[1], zA[2], zA[3]);
        dstA[1] = make_float4(zA[4], zA[5], zA[6], zA[7]);
        float4* dstB = (float4*)(zT + (rowA + 1) * 8);
        dstB[0] = make_float4(zB[0], zB[1], zB[2], zB[3]);
        dstB[1] = make_float4(zB[4], zB[5], zB[6], zB[7]);
    }
}

// ---------- Kernel 2: gelu readout + T10 + X_out ----------
__global__ __launch_bounds__(256) void readout_kernel(
    const float* __restrict__ zT,
    const float* __restrict__ Fin,
    const float* __restrict__ TRv,
    const int*   __restrict__ fa_len,
    const float* __restrict__ Wr1, const float* __restrict__ br1,
    const float* __restrict__ Wr2, const float* __restrict__ br2,
    const float* __restrict__ Wr3, const float* __restrict__ br3,
    float* __restrict__ out)
{
    __shared__ float h1s[32][200];     // per-row h1
    __shared__ float w2s[40][200];     // Wr2 chunk (5 chunks of 40 rows)
    const int tid = threadIdx.x;
    const int g = tid >> 3, sub = tid & 7;
    const int row = blockIdx.x * 32 + g;

    float4 za = *(const float4*)(zT + row * 8);
    float4 zb = *(const float4*)(zT + row * 8 + 4);

#pragma unroll 5
    for (int t = 0; t < 25; ++t) {
        int j = sub + 8 * t;
        const float* w = Wr1 + j * 8;
        float4 wa = *(const float4*)(w);
        float4 wb = *(const float4*)(w + 4);
        float acc = br1[j];
        acc = fmaf(wa.x, za.x, acc);
        acc = fmaf(wa.y, za.y, acc);
        acc = fmaf(wa.z, za.z, acc);
        acc = fmaf(wa.w, za.w, acc);
        acc = fmaf(wb.x, zb.x, acc);
        acc = fmaf(wb.y, zb.y, acc);
        acc = fmaf(wb.z, zb.z, acc);
        acc = fmaf(wb.w, zb.w, acc);
        h1s[g][j] = gelu_exact(acc);
    }
    __syncthreads();

    float tacc = 0.0f;
    for (int c = 0; c < 5; ++c) {
        const float4* src4 = (const float4*)(Wr2 + c * 8000);
        float4* dst4 = (float4*)(&w2s[0][0]);
#pragma unroll
        for (int it = 0; it < 8; ++it) {
            int idx = tid + it * 256;
            if (idx < 2000) dst4[idx] = src4[idx];
        }
        __syncthreads();
#pragma unroll
        for (int t = 0; t < 5; ++t) {
            int ol = sub + 8 * t;
            int o  = c * 40 + ol;
            float acc = br2[o];
            const float4* wv = (const float4*)(&w2s[ol][0]);
            const float4* hv = (const float4*)(&h1s[g][0]);
#pragma unroll 10
            for (int q = 0; q < 50; ++q) {
                float4 a = wv[q], b = hv[q];
                acc = fmaf(a.x, b.x, acc);
                acc = fmaf(a.y, b.y, acc);
                acc = fmaf(a.z, b.z, acc);
                acc = fmaf(a.w, b.w, acc);
            }
            float h2 = gelu_exact(acc);
            tacc = fmaf(Wr3[o], h2, tacc);
        }
        __syncthreads();
    }

    tacc += __shfl_xor(tacc, 1, 8);
    tacc += __shfl_xor(tacc, 2, 8);
    tacc += __shfl_xor(tacc, 4, 8);
    float tval = tacc + br3[0];
    float sig  = __fdividef(1.0f, 1.0f + __expf(-tval));
    float T10  = 0.1f + 6.9f * sig;
    float R1   = 1.0f / T10;
    float E    = __expf(-TRv[row] * R1);

    float xo[4]; float ssum = 0.f;
#pragma unroll
    for (int t = 0; t < 4; ++t) {
        int p = sub + 8 * t;
        float fa = Fin[row * 32 + p];
        float sn = __sinf(fa), cs = __cosf(fa);
        float v = __fdividef((1.0f - E) * sn, 1.0f - cs * E);
        xo[t] = v; ssum += v;
    }
    ssum += __shfl_xor(ssum, 1, 8);
    ssum += __shfl_xor(ssum, 2, 8);
    ssum += __shfl_xor(ssum, 4, 8);
    float mean2 = ssum / (float)fa_len[row];
    float inv   = __fdividef(1.0f, mean2);
#pragma unroll
    for (int t = 0; t < 4; ++t) {
        int p = sub + 8 * t;
        out[row * 32 + p] = xo[t] * inv;
    }
    if (sub == 0) {
        out[B_ROWS * L_SEQ + row] = T10;
        out[B_ROWS * L_SEQ + B_ROWS + row] = 1.0f;
    }
}

extern "C" void kernel_launch(void* const* d_in, const int* in_sizes, int n_in,
                              void* d_out, int out_size, void* d_ws, size_t ws_size,
                              hipStream_t stream) {
    const float* Xin  = (const float*)d_in[0];
    const float* Fin  = (const float*)d_in[1];
    const float* TRv  = (const float*)d_in[2];
    const float* Wi   = (const float*)d_in[3];
    const float* bi   = (const float*)d_in[4];
    const float* W1g  = (const float*)d_in[5];
    const float* b1g  = (const float*)d_in[6];
    const float* W2g  = (const float*)d_in[7];
    const float* b2g  = (const float*)d_in[8];
    const float* Wr1  = (const float*)d_in[9];
    const float* br1  = (const float*)d_in[10];
    const float* Wr2  = (const float*)d_in[11];
    const float* br2  = (const float*)d_in[12];
    const float* Wr3  = (const float*)d_in[13];
    const float* br3  = (const float*)d_in[14];
    const int*   flen = (const int*)d_in[16];

    float* outp = (float*)d_out;
    float* zT   = (float*)d_ws;

    ode_kernel<<<dim3(B_ROWS / 32), dim3(256), 0, stream>>>(
        Xin, Fin, flen, Wi, bi, W1g, b1g, W2g, b2g, zT);
    readout_kernel<<<dim3(B_ROWS / 32), dim3(256), 0, stream>>>(
        zT, Fin, TRv, flen, Wr1, br1, Wr2, br2, Wr3, br3, outp);
}

// Round 5
// 338.909 us; speedup vs baseline: 5.4105x; 3.3889x over previous
//
#include <hip/hip_runtime.h>
#include <hip/hip_bf16.h>

// Problem constants (fixed by the reference)
#define B_ROWS 16384
#define L_SEQ  32

typedef _Float16 f16;
typedef __attribute__((ext_vector_type(8))) _Float16 f16x8;
typedef __attribute__((ext_vector_type(4))) float f32x4;
typedef __attribute__((ext_vector_type(4))) unsigned int u32x4;

// ---------- fast device math ----------
__device__ __forceinline__ unsigned pkh(float a, float b) {
    return __builtin_bit_cast(unsigned, __builtin_amdgcn_cvt_pkrtz(a, b));
}
__device__ __forceinline__ float tanh_fast(float x) {
    float e = __expf(2.0f * x);
    float r = __builtin_amdgcn_rcpf(e + 1.0f);
    return fmaf(-2.0f, r, 1.0f);
}
__device__ __forceinline__ float gelu_exact(float x) {
    return 0.5f * x * (1.0f + erff(x * 0.70710678118654752440f));
}

// ---------- Kernel 1: preprocessing + MFMA RK4 neural-ODE ----------
// One wave owns 16 rows (the 16 MFMA columns). Block = 4 waves = 64 rows.
// Weights live in VGPR fragments (loop-invariant). h does a per-wave LDS
// round-trip to relayout C-frag -> B-frag. z-master is f32, distributed
// 2 components/lane matching the C-layout (row = 4q+r, col = n).
__global__ __launch_bounds__(256, 1) void ode_kernel(
    const float* __restrict__ Xin, const float* __restrict__ Fin,
    const int*   __restrict__ fa_len,
    const float* __restrict__ Wi,  const float* __restrict__ bi,
    const float* __restrict__ W1g, const float* __restrict__ b1g,
    const float* __restrict__ W2g, const float* __restrict__ b2g,
    float* __restrict__ zT)
{
    __shared__ __align__(16) float xm[64 * 132];               // [row][i<33][c<4], 528B row stride
    __shared__ __align__(16) unsigned short hl[4 * 16 * 256];  // per-wave h: [wave][row n][256 f16]
#define XM(r_, i_, c_) xm[(r_) * 132 + (i_) * 4 + (c_)]

    const int tid = threadIdx.x;
    const int g16 = tid >> 4, sub = tid & 15;

    // ---- preprocessing (push_zeros + fill, identical math to r3 kernel) ----
    float mean_r[4]; int fl_r[4];
#pragma unroll
    for (int r = 0; r < 4; ++r) {
        const int row_l = g16 * 4 + r;
        const int row   = blockIdx.x * 64 + row_l;
        const float* Xr = Xin + row * L_SEQ;
        const float* Fr = Fin + row * L_SEQ;
        float xr0 = Xr[sub], xr1 = Xr[sub + 16];
        float fr0 = Fr[sub], fr1 = Fr[sub + 16];
        fl_r[r] = fa_len[row];
        float s = xr0 + xr1;
        s += __shfl_xor(s, 1, 16);
        s += __shfl_xor(s, 2, 16);
        s += __shfl_xor(s, 4, 16);
        s += __shfl_xor(s, 8, 16);
        mean_r[r] = s / (float)fl_r[r];
        XM(row_l, sub, 0)      = fr0; XM(row_l, sub, 1)      = xr0;
        XM(row_l, sub + 16, 0) = fr1; XM(row_l, sub + 16, 1) = xr1;
    }
    __syncthreads();

    float ff[4][2], xf[4][2];
#pragma unroll
    for (int r = 0; r < 4; ++r) {
        const int row_l = g16 * 4 + r;
        const int fl = fl_r[r];
        const float mean = mean_r[r];
        const int shift = L_SEQ - fl;
        int lsrc  = fl - 1 - shift;
        int lsrcC = lsrc < 0 ? 0 : lsrc;
        float lastX = (lsrc >= 0) ? (XM(row_l, lsrcC, 1) / mean) : 0.0f;
        float lastF = XM(row_l, fl - 1, 0);
#pragma unroll
        for (int u = 0; u < 2; ++u) {
            int p = sub + u * 16;
            int src = p - shift;
            int sc  = src < 0 ? 0 : src;
            float fraw = XM(row_l, sc, 0);
            float xraw = XM(row_l, sc, 1);
            ff[r][u] = (src >= 0) ? fraw : lastF;
            xf[r][u] = (src >= 0) ? (xraw / mean) : lastX;
        }
    }
    __syncthreads();
#pragma unroll
    for (int r = 0; r < 4; ++r) {
        const int row_l = g16 * 4 + r;
#pragma unroll
        for (int u = 0; u < 2; ++u) {
            int p = sub + u * 16;
            XM(row_l, p, 0) = ff[r][u];
            XM(row_l, p, 1) = xf[r][u];
        }
    }
    __syncthreads();
#pragma unroll
    for (int r = 0; r < 4; ++r) {
        const int row_l = g16 * 4 + r;
#pragma unroll
        for (int u = 0; u < 2; ++u) {
            int p = sub + u * 16;
            int qd = (p == 0) ? 1 : p;         // m[0] = x[1]-x[0]
            XM(row_l, p, 2) = XM(row_l, qd, 0) - XM(row_l, qd - 1, 0);
            XM(row_l, p, 3) = XM(row_l, qd, 1) - XM(row_l, qd - 1, 1);
        }
    }
    __syncthreads();

    // ---- MFMA-phase lane mapping ----
    const int wv   = tid >> 6;
    const int lane = tid & 63;
    const int n    = lane & 15;     // MFMA column = row-in-wave
    const int q    = lane >> 4;     // lane quarter
    const int rowl = wv * 16 + n;
    const int rowg = blockIdx.x * 64 + rowl;

    // A-frag layout (16x16x32 f16): lane holds A[m=lane&15][k], elems e:
    //   k = (e>>2)*16 + 4q + (e&3)   (two stacked K-16 blocks)
    // Layer1 A = W1 K-padded: k<8 = W1 row, k=8 = b1 (vs 1.0 on z side).
    u32x4 a1[16];
#pragma unroll
    for (int t = 0; t < 16; ++t) {
        const float* wr = W1g + (t * 16 + n) * 8 + (q < 2 ? q * 4 : 0);
        float4 w4 = *(const float4*)wr;
        float b1v = b1g[t * 16 + n];
        unsigned d0 = (q < 2) ? pkh(w4.x, w4.y) : (q == 2 ? pkh(b1v, 0.0f) : 0u);
        unsigned d1 = (q < 2) ? pkh(w4.z, w4.w) : 0u;
        a1[t] = (u32x4){d0, d1, 0u, 0u};
    }
    // Layer2 A = W2 [16 x 256], 8 K-steps
    u32x4 a2[8];
#pragma unroll
    for (int kk = 0; kk < 8; ++kk) {
        const float* w2r = W2g + n * 256 + kk * 32 + 4 * q;
        float4 p0 = *(const float4*)(w2r);
        float4 p1 = *(const float4*)(w2r + 16);
        a2[kk] = (u32x4){pkh(p0.x, p0.y), pkh(p0.z, p0.w), pkh(p1.x, p1.y), pkh(p1.z, p1.w)};
    }
    // b2 seed for the layer2 accumulator (f32 exact)
    f32x4 c2seed;
#pragma unroll
    for (int r = 0; r < 4; ++r) c2seed[r] = b2g[4 * q + r];

    // z0 distributed: lane holds z[2q], z[2q+1] (f32 master)
    float f0 = XM(rowl, 0, 0), X0 = XM(rowl, 0, 1);
    float z0 = fmaf(Wi[(2 * q) * 2], f0, fmaf(Wi[(2 * q) * 2 + 1], X0, bi[2 * q]));
    float z1 = fmaf(Wi[(2 * q + 1) * 2], f0, fmaf(Wi[(2 * q + 1) * 2 + 1], X0, bi[2 * q + 1]));

    // h LDS base: row stride 512B, q slot swizzled by n (both sides use it)
    char* hb = (char*)hl + wv * 8192 + n * 512 + ((q ^ (n & 3)) << 4);
    const int bp0 = n * 4, bp1 = (16 + n) * 4, bp2 = (32 + n) * 4, bp3 = (48 + n) * 4;
    const f32x4 zero4 = {0.f, 0.f, 0.f, 0.f};

    auto FEVAL = [&](float zza, float zzb, float d0c, float d1c, float& ko0, float& ko1) {
        // build B(z) frag: gather the 4 z-pairs of this column via bpermute
        unsigned myz = pkh(zza, zzb);
        int g0 = __builtin_amdgcn_ds_bpermute(bp0, (int)myz);
        int g1 = __builtin_amdgcn_ds_bpermute(bp1, (int)myz);
        int g2 = __builtin_amdgcn_ds_bpermute(bp2, (int)myz);
        int g3 = __builtin_amdgcn_ds_bpermute(bp3, (int)myz);
        unsigned bz0 = (q == 0) ? (unsigned)g0 : (q == 1) ? (unsigned)g2
                     : (q == 2) ? 0x3C00u : 0u;                     // k=8: 1.0 (bias)
        unsigned bz1 = (q == 0) ? (unsigned)g1 : (q == 1) ? (unsigned)g3 : 0u;
        f16x8 bz = __builtin_bit_cast(f16x8, (u32x4){bz0, bz1, 0u, 0u});

        // layer 1: 16 independent MFMAs -> h tiles
        f32x4 c1[16];
#pragma unroll
        for (int t = 0; t < 16; ++t)
            c1[t] = __builtin_amdgcn_mfma_f32_16x16x32_f16(
                __builtin_bit_cast(f16x8, a1[t]), bz, zero4, 0, 0, 0);

        // relu + pack + store (C-frag -> B-frag relayout via LDS)
#pragma unroll
        for (int t = 0; t < 16; ++t) {
            float v0 = fmaxf(c1[t][0], 0.f), v1 = fmaxf(c1[t][1], 0.f);
            float v2 = fmaxf(c1[t][2], 0.f), v3 = fmaxf(c1[t][3], 0.f);
            *(uint2*)(hb + ((t >> 1) * 64 + (t & 1) * 8)) =
                make_uint2(pkh(v0, v1), pkh(v2, v3));
        }

        // layer 2: 8-step K chain, b2-seeded accumulator
        f32x4 c2 = c2seed;
#pragma unroll
        for (int kk = 0; kk < 8; ++kk) {
            u32x4 hv = *(const u32x4*)(hb + kk * 64);
            c2 = __builtin_amdgcn_mfma_f32_16x16x32_f16(
                __builtin_bit_cast(f16x8, a2[kk]), __builtin_bit_cast(f16x8, hv), c2, 0, 0, 0);
        }

        // g = tanh(G); lane holds G[4q..4q+3] -> k[2q], k[2q+1]
        float t0 = tanh_fast(c2[0]), t1 = tanh_fast(c2[1]);
        float t2 = tanh_fast(c2[2]), t3 = tanh_fast(c2[3]);
        ko0 = fmaf(t0, d0c, t1 * d1c);
        ko1 = fmaf(t2, d0c, t3 * d1c);
    };

    // ---- 31 intervals x 2 substeps of RK4 ----
#pragma unroll 1
    for (int i = 0; i < 31; ++i) {
        float4 P0 = *(const float4*)&XM(rowl, i, 0);
        float4 P1 = *(const float4*)&XM(rowl, i + 1, 0);
        float m0f = P0.z, m0X = P0.w, m1f = P1.z, m1X = P1.w;
        float df  = P0.x - P1.x, dXx = P0.y - P1.y;

        float d25f = fmaf(-1.125f, df,  fmaf(0.1875f, m0f, -0.3125f * m1f));
        float d25X = fmaf(-1.125f, dXx, fmaf(0.1875f, m0X, -0.3125f * m1X));
        float d50f = fmaf(-1.5f,   df,  fmaf(-0.25f,  m0f, -0.25f   * m1f));
        float d50X = fmaf(-1.5f,   dXx, fmaf(-0.25f,  m0X, -0.25f   * m1X));
        float d75f = fmaf(-1.125f, df,  fmaf(-0.3125f, m0f, 0.1875f * m1f));
        float d75X = fmaf(-1.125f, dXx, fmaf(-0.3125f, m0X, 0.1875f * m1X));

#pragma unroll 1
        for (int ssi = 0; ssi < 2; ++ssi) {
            float daf = ssi ? d50f : m0f,  daX = ssi ? d50X : m0X;
            float dbf = ssi ? d75f : d25f, dbX = ssi ? d75X : d25X;
            float ddf = ssi ? m1f  : d50f, ddX = ssi ? m1X  : d50X;

            float k1a, k1b, k2a, k2b, k3a, k3b, k4a, k4b, zza, zzb;
            FEVAL(z0, z1, daf, daX, k1a, k1b);
            zza = fmaf(0.25f, k1a, z0); zzb = fmaf(0.25f, k1b, z1);
            FEVAL(zza, zzb, dbf, dbX, k2a, k2b);
            zza = fmaf(0.25f, k2a, z0); zzb = fmaf(0.25f, k2b, z1);
            FEVAL(zza, zzb, dbf, dbX, k3a, k3b);
            zza = fmaf(0.5f, k3a, z0);  zzb = fmaf(0.5f, k3b, z1);
            FEVAL(zza, zzb, ddf, ddX, k4a, k4b);

            float ka = fmaf(2.f, k2a, k1a); ka = fmaf(2.f, k3a, ka);
            float kb = fmaf(2.f, k2b, k1b); kb = fmaf(2.f, k3b, kb);
            z0 = fmaf(1.f / 12.f, ka + k4a, z0);
            z1 = fmaf(1.f / 12.f, kb + k4b, z1);
        }
    }

    *(float2*)(zT + rowg * 8 + 2 * q) = make_float2(z0, z1);
#undef XM
}

// ---------- Kernel 2: gelu readout + T10 + X_out (unchanged) ----------
__global__ __launch_bounds__(256) void readout_kernel(
    const float* __restrict__ zT,
    const float* __restrict__ Fin,
    const float* __restrict__ TRv,
    const int*   __restrict__ fa_len,
    const float* __restrict__ Wr1, const float* __restrict__ br1,
    const float* __restrict__ Wr2, const float* __restrict__ br2,
    const float* __restrict__ Wr3, const float* __restrict__ br3,
    float* __restrict__ out)
{
    __shared__ float h1s[32][200];
    __shared__ float w2s[40][200];
    const int tid = threadIdx.x;
    const int g = tid >> 3, sub = tid & 7;
    const int row = blockIdx.x * 32 + g;

    float4 za = *(const float4*)(zT + row * 8);
    float4 zb = *(const float4*)(zT + row * 8 + 4);

#pragma unroll 5
    for (int t = 0; t < 25; ++t) {
        int j = sub + 8 * t;
        const float* w = Wr1 + j * 8;
        float4 wa = *(const float4*)(w);
        float4 wb = *(const float4*)(w + 4);
        float acc = br1[j];
        acc = fmaf(wa.x, za.x, acc);
        acc = fmaf(wa.y, za.y, acc);
        acc = fmaf(wa.z, za.z, acc);
        acc = fmaf(wa.w, za.w, acc);
        acc = fmaf(wb.x, zb.x, acc);
        acc = fmaf(wb.y, zb.y, acc);
        acc = fmaf(wb.z, zb.z, acc);
        acc = fmaf(wb.w, zb.w, acc);
        h1s[g][j] = gelu_exact(acc);
    }
    __syncthreads();

    float tacc = 0.0f;
    for (int c = 0; c < 5; ++c) {
        const float4* src4 = (const float4*)(Wr2 + c * 8000);
        float4* dst4 = (float4*)(&w2s[0][0]);
#pragma unroll
        for (int it = 0; it < 8; ++it) {
            int idx = tid + it * 256;
            if (idx < 2000) dst4[idx] = src4[idx];
        }
        __syncthreads();
#pragma unroll
        for (int t = 0; t < 5; ++t) {
            int ol = sub + 8 * t;
            int o  = c * 40 + ol;
            float acc = br2[o];
            const float4* wvv = (const float4*)(&w2s[ol][0]);
            const float4* hv = (const float4*)(&h1s[g][0]);
#pragma unroll 10
            for (int qq = 0; qq < 50; ++qq) {
                float4 a = wvv[qq], b = hv[qq];
                acc = fmaf(a.x, b.x, acc);
                acc = fmaf(a.y, b.y, acc);
                acc = fmaf(a.z, b.z, acc);
                acc = fmaf(a.w, b.w, acc);
            }
            float h2 = gelu_exact(acc);
            tacc = fmaf(Wr3[o], h2, tacc);
        }
        __syncthreads();
    }

    tacc += __shfl_xor(tacc, 1, 8);
    tacc += __shfl_xor(tacc, 2, 8);
    tacc += __shfl_xor(tacc, 4, 8);
    float tval = tacc + br3[0];
    float sig  = __fdividef(1.0f, 1.0f + __expf(-tval));
    float T10  = 0.1f + 6.9f * sig;
    float R1   = 1.0f / T10;
    float E    = __expf(-TRv[row] * R1);

    float xo[4]; float ssum = 0.f;
#pragma unroll
    for (int t = 0; t < 4; ++t) {
        int p = sub + 8 * t;
        float fa = Fin[row * 32 + p];
        float sn = __sinf(fa), cs = __cosf(fa);
        float v = __fdividef((1.0f - E) * sn, 1.0f - cs * E);
        xo[t] = v; ssum += v;
    }
    ssum += __shfl_xor(ssum, 1, 8);
    ssum += __shfl_xor(ssum, 2, 8);
    ssum += __shfl_xor(ssum, 4, 8);
    float mean2 = ssum / (float)fa_len[row];
    float inv   = __fdividef(1.0f, mean2);
#pragma unroll
    for (int t = 0; t < 4; ++t) {
        int p = sub + 8 * t;
        out[row * 32 + p] = xo[t] * inv;
    }
    if (sub == 0) {
        out[B_ROWS * L_SEQ + row] = T10;
        out[B_ROWS * L_SEQ + B_ROWS + row] = 1.0f;
    }
}

extern "C" void kernel_launch(void* const* d_in, const int* in_sizes, int n_in,
                              void* d_out, int out_size, void* d_ws, size_t ws_size,
                              hipStream_t stream) {
    const float* Xin  = (const float*)d_in[0];
    const float* Fin  = (const float*)d_in[1];
    const float* TRv  = (const float*)d_in[2];
    const float* Wi   = (const float*)d_in[3];
    const float* bi   = (const float*)d_in[4];
    const float* W1g  = (const float*)d_in[5];
    const float* b1g  = (const float*)d_in[6];
    const float* W2g  = (const float*)d_in[7];
    const float* b2g  = (const float*)d_in[8];
    const float* Wr1  = (const float*)d_in[9];
    const float* br1  = (const float*)d_in[10];
    const float* Wr2  = (const float*)d_in[11];
    const float* br2  = (const float*)d_in[12];
    const float* Wr3  = (const float*)d_in[13];
    const float* br3  = (const float*)d_in[14];
    const int*   flen = (const int*)d_in[16];

    float* outp = (float*)d_out;
    float* zT   = (float*)d_ws;

    ode_kernel<<<dim3(B_ROWS / 64), dim3(256), 0, stream>>>(
        Xin, Fin, flen, Wi, bi, W1g, b1g, W2g, b2g, zT);
    readout_kernel<<<dim3(B_ROWS / 32), dim3(256), 0, stream>>>(
        zT, Fin, TRv, flen, Wr1, br1, Wr2, br2, Wr3, br3, outp);
}

// Round 7
// 304.732 us; speedup vs baseline: 6.0173x; 1.1122x over previous
//
#include <hip/hip_runtime.h>
#include <hip/hip_bf16.h>

// Problem constants (fixed by the reference)
#define B_ROWS 16384
#define L_SEQ  32

typedef _Float16 f16;
typedef __attribute__((ext_vector_type(8))) _Float16 f16x8;
typedef __attribute__((ext_vector_type(4))) float f32x4;
typedef __attribute__((ext_vector_type(4))) unsigned int u32x4;

// ---------- fast device math ----------
__device__ __forceinline__ unsigned pkh(float a, float b) {
    return __builtin_bit_cast(unsigned, __builtin_amdgcn_cvt_pkrtz(a, b));
}
__device__ __forceinline__ float tanh_fast(float x) {
    float e = __expf(2.0f * x);
    float r = __builtin_amdgcn_rcpf(e + 1.0f);
    return fmaf(-2.0f, r, 1.0f);
}
__device__ __forceinline__ float gelu_exact(float x) {
    return 0.5f * x * (1.0f + erff(x * 0.70710678118654752440f));
}

// ---------- Kernel 1: preprocessing + MFMA RK4 neural-ODE ----------
// One wave owns 16 rows (the 16 MFMA columns). Block = 4 waves = 64 rows.
// Key identity (validated r5): layer-1 C-frag reg r of lane (q,n) holds
// h[16t+4q+r][n], and layer-2's B-frag for K-chunk kk needs exactly
// {tile 2kk regs 0..3, tile 2kk+1 regs 0..3} in lane (q,n) -> the C->B
// relayout is LANE-LOCAL (relu+pack only, no LDS round-trip).
__global__ __launch_bounds__(256, 1) void ode_kernel(
    const float* __restrict__ Xin, const float* __restrict__ Fin,
    const int*   __restrict__ fa_len,
    const float* __restrict__ Wi,  const float* __restrict__ bi,
    const float* __restrict__ W1g, const float* __restrict__ b1g,
    const float* __restrict__ W2g, const float* __restrict__ b2g,
    float* __restrict__ zT)
{
    __shared__ __align__(16) float xm[64 * 132];   // [row][i<33][c<4], 528B row stride
#define XM(r_, i_, c_) xm[(r_) * 132 + (i_) * 4 + (c_)]

    const int tid = threadIdx.x;
    const int g16 = tid >> 4, sub = tid & 15;

    // ---- preprocessing (push_zeros + fill; identical to r5) ----
    float mean_r[4]; int fl_r[4];
#pragma unroll
    for (int r = 0; r < 4; ++r) {
        const int row_l = g16 * 4 + r;
        const int row   = blockIdx.x * 64 + row_l;
        const float* Xr = Xin + row * L_SEQ;
        const float* Fr = Fin + row * L_SEQ;
        float xr0 = Xr[sub], xr1 = Xr[sub + 16];
        float fr0 = Fr[sub], fr1 = Fr[sub + 16];
        fl_r[r] = fa_len[row];
        float s = xr0 + xr1;
        s += __shfl_xor(s, 1, 16);
        s += __shfl_xor(s, 2, 16);
        s += __shfl_xor(s, 4, 16);
        s += __shfl_xor(s, 8, 16);
        mean_r[r] = s / (float)fl_r[r];
        XM(row_l, sub, 0)      = fr0; XM(row_l, sub, 1)      = xr0;
        XM(row_l, sub + 16, 0) = fr1; XM(row_l, sub + 16, 1) = xr1;
    }
    __syncthreads();

    float ff[4][2], xf[4][2];
#pragma unroll
    for (int r = 0; r < 4; ++r) {
        const int row_l = g16 * 4 + r;
        const int fl = fl_r[r];
        const float mean = mean_r[r];
        const int shift = L_SEQ - fl;
        int lsrc  = fl - 1 - shift;
        int lsrcC = lsrc < 0 ? 0 : lsrc;
        float lastX = (lsrc >= 0) ? (XM(row_l, lsrcC, 1) / mean) : 0.0f;
        float lastF = XM(row_l, fl - 1, 0);
#pragma unroll
        for (int u = 0; u < 2; ++u) {
            int p = sub + u * 16;
            int src = p - shift;
            int sc  = src < 0 ? 0 : src;
            float fraw = XM(row_l, sc, 0);
            float xraw = XM(row_l, sc, 1);
            ff[r][u] = (src >= 0) ? fraw : lastF;
            xf[r][u] = (src >= 0) ? (xraw / mean) : lastX;
        }
    }
    __syncthreads();
#pragma unroll
    for (int r = 0; r < 4; ++r) {
        const int row_l = g16 * 4 + r;
#pragma unroll
        for (int u = 0; u < 2; ++u) {
            int p = sub + u * 16;
            XM(row_l, p, 0) = ff[r][u];
            XM(row_l, p, 1) = xf[r][u];
        }
    }
    __syncthreads();
#pragma unroll
    for (int r = 0; r < 4; ++r) {
        const int row_l = g16 * 4 + r;
#pragma unroll
        for (int u = 0; u < 2; ++u) {
            int p = sub + u * 16;
            int qd = (p == 0) ? 1 : p;         // m[0] = x[1]-x[0]
            XM(row_l, p, 2) = XM(row_l, qd, 0) - XM(row_l, qd - 1, 0);
            XM(row_l, p, 3) = XM(row_l, qd, 1) - XM(row_l, qd - 1, 1);
        }
    }
    __syncthreads();

    // ---- MFMA-phase lane mapping ----
    const int wv   = tid >> 6;
    const int lane = tid & 63;
    const int n    = lane & 15;     // MFMA column = row-in-wave
    const int q    = lane >> 4;     // lane quarter
    const int rowl = wv * 16 + n;
    const int rowg = blockIdx.x * 64 + rowl;

    // Layer1 A = W1 K-padded to 32: k<8 = W1 row, k=8 = b1 (vs 1.0 on z side).
    u32x4 a1[16];
#pragma unroll
    for (int t = 0; t < 16; ++t) {
        const float* wr = W1g + (t * 16 + n) * 8 + (q < 2 ? q * 4 : 0);
        float4 w4 = *(const float4*)wr;
        float b1v = b1g[t * 16 + n];
        unsigned d0 = (q < 2) ? pkh(w4.x, w4.y) : (q == 2 ? pkh(b1v, 0.0f) : 0u);
        unsigned d1 = (q < 2) ? pkh(w4.z, w4.w) : 0u;
        a1[t] = (u32x4){d0, d1, 0u, 0u};
    }
    // Layer2 A = W2 [16 x 256], 8 K-steps
    u32x4 a2[8];
#pragma unroll
    for (int kk = 0; kk < 8; ++kk) {
        const float* w2r = W2g + n * 256 + kk * 32 + 4 * q;
        float4 p0 = *(const float4*)(w2r);
        float4 p1 = *(const float4*)(w2r + 16);
        a2[kk] = (u32x4){pkh(p0.x, p0.y), pkh(p0.z, p0.w), pkh(p1.x, p1.y), pkh(p1.z, p1.w)};
    }
    // b2 seed for one layer2 chain (f32 exact)
    f32x4 c2seed;
#pragma unroll
    for (int r = 0; r < 4; ++r) c2seed[r] = b2g[4 * q + r];

    // z0 distributed: lane holds z[2q], z[2q+1] (f32 master)
    float f0 = XM(rowl, 0, 0), X0 = XM(rowl, 0, 1);
    float z0 = fmaf(Wi[(2 * q) * 2], f0, fmaf(Wi[(2 * q) * 2 + 1], X0, bi[2 * q]));
    float z1 = fmaf(Wi[(2 * q + 1) * 2], f0, fmaf(Wi[(2 * q + 1) * 2 + 1], X0, bi[2 * q + 1]));

    // bpermute byte-index: lane (q,n) gathers z-pairs from lanes (q&1)*32+n (+16)
    const int bpi = (((q & 1) << 5) + n) << 2;
    const f32x4 zero4 = {0.f, 0.f, 0.f, 0.f};

    auto FEVAL = [&](float zza, float zzb, float d0c, float d1c, float& ko0, float& ko1) {
        // B(z) frag: 2 bpermutes; k=8 bias slot gets 1.0 for q==2
        unsigned myz = pkh(zza, zzb);
        int b0 = __builtin_amdgcn_ds_bpermute(bpi, (int)myz);
        int b1 = __builtin_amdgcn_ds_bpermute(bpi + 64, (int)myz);
        unsigned bz0 = (q < 2) ? (unsigned)b0 : (q == 2 ? 0x3C00u : 0u);
        unsigned bz1 = (q < 2) ? (unsigned)b1 : 0u;
        f16x8 bz = __builtin_bit_cast(f16x8, (u32x4){bz0, bz1, 0u, 0u});

        // layer 1: 16 independent MFMAs -> h tiles (C-frag, lane-local)
        f32x4 c1[16];
#pragma unroll
        for (int t = 0; t < 16; ++t)
            c1[t] = __builtin_amdgcn_mfma_f32_16x16x32_f16(
                __builtin_bit_cast(f16x8, a1[t]), bz, zero4, 0, 0, 0);

        // relu + pack: C-frag pair (2kk,2kk+1) IS layer-2's B-frag kk
        u32x4 hf[8];
#pragma unroll
        for (int kk = 0; kk < 8; ++kk) {
            float v0 = fmaxf(c1[2 * kk][0], 0.f),     v1 = fmaxf(c1[2 * kk][1], 0.f);
            float v2 = fmaxf(c1[2 * kk][2], 0.f),     v3 = fmaxf(c1[2 * kk][3], 0.f);
            float w0 = fmaxf(c1[2 * kk + 1][0], 0.f), w1 = fmaxf(c1[2 * kk + 1][1], 0.f);
            float w2 = fmaxf(c1[2 * kk + 1][2], 0.f), w3 = fmaxf(c1[2 * kk + 1][3], 0.f);
            hf[kk] = (u32x4){pkh(v0, v1), pkh(v2, v3), pkh(w0, w1), pkh(w2, w3)};
        }

        // layer 2: two independent 4-MFMA chains (halves serial C-dep latency)
        f32x4 c2a = c2seed, c2b = zero4;
#pragma unroll
        for (int kk = 0; kk < 4; ++kk) {
            c2a = __builtin_amdgcn_mfma_f32_16x16x32_f16(
                __builtin_bit_cast(f16x8, a2[kk]), __builtin_bit_cast(f16x8, hf[kk]), c2a, 0, 0, 0);
            c2b = __builtin_amdgcn_mfma_f32_16x16x32_f16(
                __builtin_bit_cast(f16x8, a2[kk + 4]), __builtin_bit_cast(f16x8, hf[kk + 4]), c2b, 0, 0, 0);
        }
        f32x4 G = c2a + c2b;

        // g = tanh(G); lane holds G[4q..4q+3] -> k[2q], k[2q+1]
        float t0 = tanh_fast(G[0]), t1 = tanh_fast(G[1]);
        float t2 = tanh_fast(G[2]), t3 = tanh_fast(G[3]);
        ko0 = fmaf(t0, d0c, t1 * d1c);
        ko1 = fmaf(t2, d0c, t3 * d1c);
    };

    // ---- 31 intervals x 2 substeps of RK4 ----
#pragma unroll 1
    for (int i = 0; i < 31; ++i) {
        float4 P0 = *(const float4*)&XM(rowl, i, 0);
        float4 P1 = *(const float4*)&XM(rowl, i + 1, 0);
        float m0f = P0.z, m0X = P0.w, m1f = P1.z, m1X = P1.w;
        float df  = P0.x - P1.x, dXx = P0.y - P1.y;

        float d25f = fmaf(-1.125f, df,  fmaf(0.1875f, m0f, -0.3125f * m1f));
        float d25X = fmaf(-1.125f, dXx, fmaf(0.1875f, m0X, -0.3125f * m1X));
        float d50f = fmaf(-1.5f,   df,  fmaf(-0.25f,  m0f, -0.25f   * m1f));
        float d50X = fmaf(-1.5f,   dXx, fmaf(-0.25f,  m0X, -0.25f   * m1X));
        float d75f = fmaf(-1.125f, df,  fmaf(-0.3125f, m0f, 0.1875f * m1f));
        float d75X = fmaf(-1.125f, dXx, fmaf(-0.3125f, m0X, 0.1875f * m1X));

#pragma unroll 1
        for (int ssi = 0; ssi < 2; ++ssi) {
            float daf = ssi ? d50f : m0f,  daX = ssi ? d50X : m0X;
            float dbf = ssi ? d75f : d25f, dbX = ssi ? d75X : d25X;
            float ddf = ssi ? m1f  : d50f, ddX = ssi ? m1X  : d50X;

            float k1a, k1b, k2a, k2b, k3a, k3b, k4a, k4b, zza, zzb;
            FEVAL(z0, z1, daf, daX, k1a, k1b);
            zza = fmaf(0.25f, k1a, z0); zzb = fmaf(0.25f, k1b, z1);
            FEVAL(zza, zzb, dbf, dbX, k2a, k2b);
            zza = fmaf(0.25f, k2a, z0); zzb = fmaf(0.25f, k2b, z1);
            FEVAL(zza, zzb, dbf, dbX, k3a, k3b);
            zza = fmaf(0.5f, k3a, z0);  zzb = fmaf(0.5f, k3b, z1);
            FEVAL(zza, zzb, ddf, ddX, k4a, k4b);

            float ka = fmaf(2.f, k2a, k1a); ka = fmaf(2.f, k3a, ka);
            float kb = fmaf(2.f, k2b, k1b); kb = fmaf(2.f, k3b, kb);
            z0 = fmaf(1.f / 12.f, ka + k4a, z0);
            z1 = fmaf(1.f / 12.f, kb + k4b, z1);
        }
    }

    *(float2*)(zT + rowg * 8 + 2 * q) = make_float2(z0, z1);
#undef XM
}

// ---------- Kernel 2: gelu readout + T10 + X_out (unchanged) ----------
__global__ __launch_bounds__(256) void readout_kernel(
    const float* __restrict__ zT,
    const float* __restrict__ Fin,
    const float* __restrict__ TRv,
    const int*   __restrict__ fa_len,
    const float* __restrict__ Wr1, const float* __restrict__ br1,
    const float* __restrict__ Wr2, const float* __restrict__ br2,
    const float* __restrict__ Wr3, const float* __restrict__ br3,
    float* __restrict__ out)
{
    __shared__ float h1s[32][200];
    __shared__ float w2s[40][200];
    const int tid = threadIdx.x;
    const int g = tid >> 3, sub = tid & 7;
    const int row = blockIdx.x * 32 + g;

    float4 za = *(const float4*)(zT + row * 8);
    float4 zb = *(const float4*)(zT + row * 8 + 4);

#pragma unroll 5
    for (int t = 0; t < 25; ++t) {
        int j = sub + 8 * t;
        const float* w = Wr1 + j * 8;
        float4 wa = *(const float4*)(w);
        float4 wb = *(const float4*)(w + 4);
        float acc = br1[j];
        acc = fmaf(wa.x, za.x, acc);
        acc = fmaf(wa.y, za.y, acc);
        acc = fmaf(wa.z, za.z, acc);
        acc = fmaf(wa.w, za.w, acc);
        acc = fmaf(wb.x, zb.x, acc);
        acc = fmaf(wb.y, zb.y, acc);
        acc = fmaf(wb.z, zb.z, acc);
        acc = fmaf(wb.w, zb.w, acc);
        h1s[g][j] = gelu_exact(acc);
    }
    __syncthreads();

    float tacc = 0.0f;
    for (int c = 0; c < 5; ++c) {
        const float4* src4 = (const float4*)(Wr2 + c * 8000);
        float4* dst4 = (float4*)(&w2s[0][0]);
#pragma unroll
        for (int it = 0; it < 8; ++it) {
            int idx = tid + it * 256;
            if (idx < 2000) dst4[idx] = src4[idx];
        }
        __syncthreads();
#pragma unroll
        for (int t = 0; t < 5; ++t) {
            int ol = sub + 8 * t;
            int o  = c * 40 + ol;
            float acc = br2[o];
            const float4* wvv = (const float4*)(&w2s[ol][0]);
            const float4* hv = (const float4*)(&h1s[g][0]);
#pragma unroll 10
            for (int qq = 0; qq < 50; ++qq) {
                float4 a = wvv[qq], b = hv[qq];
                acc = fmaf(a.x, b.x, acc);
                acc = fmaf(a.y, b.y, acc);
                acc = fmaf(a.z, b.z, acc);
                acc = fmaf(a.w, b.w, acc);
            }
            float h2 = gelu_exact(acc);
            tacc = fmaf(Wr3[o], h2, tacc);
        }
        __syncthreads();
    }

    tacc += __shfl_xor(tacc, 1, 8);
    tacc += __shfl_xor(tacc, 2, 8);
    tacc += __shfl_xor(tacc, 4, 8);
    float tval = tacc + br3[0];
    float sig  = __fdividef(1.0f, 1.0f + __expf(-tval));
    float T10  = 0.1f + 6.9f * sig;
    float R1   = 1.0f / T10;
    float E    = __expf(-TRv[row] * R1);

    float xo[4]; float ssum = 0.f;
#pragma unroll
    for (int t = 0; t < 4; ++t) {
        int p = sub + 8 * t;
        float fa = Fin[row * 32 + p];
        float sn = __sinf(fa), cs = __cosf(fa);
        float v = __fdividef((1.0f - E) * sn, 1.0f - cs * E);
        xo[t] = v; ssum += v;
    }
    ssum += __shfl_xor(ssum, 1, 8);
    ssum += __shfl_xor(ssum, 2, 8);
    ssum += __shfl_xor(ssum, 4, 8);
    float mean2 = ssum / (float)fa_len[row];
    float inv   = __fdividef(1.0f, mean2);
#pragma unroll
    for (int t = 0; t < 4; ++t) {
        int p = sub + 8 * t;
        out[row * 32 + p] = xo[t] * inv;
    }
    if (sub == 0) {
        out[B_ROWS * L_SEQ + row] = T10;
        out[B_ROWS * L_SEQ + B_ROWS + row] = 1.0f;
    }
}

extern "C" void kernel_launch(void* const* d_in, const int* in_sizes, int n_in,
                              void* d_out, int out_size, void* d_ws, size_t ws_size,
                              hipStream_t stream) {
    const float* Xin  = (const float*)d_in[0];
    const float* Fin  = (const float*)d_in[1];
    const float* TRv  = (const float*)d_in[2];
    const float* Wi   = (const float*)d_in[3];
    const float* bi   = (const float*)d_in[4];
    const float* W1g  = (const float*)d_in[5];
    const float* b1g  = (const float*)d_in[6];
    const float* W2g  = (const float*)d_in[7];
    const float* b2g  = (const float*)d_in[8];
    const float* Wr1  = (const float*)d_in[9];
    const float* br1  = (const float*)d_in[10];
    const float* Wr2  = (const float*)d_in[11];
    const float* br2  = (const float*)d_in[12];
    const float* Wr3  = (const float*)d_in[13];
    const float* br3  = (const float*)d_in[14];
    const int*   flen = (const int*)d_in[16];

    float* outp = (float*)d_out;
    float* zT   = (float*)d_ws;

    ode_kernel<<<dim3(B_ROWS / 64), dim3(256), 0, stream>>>(
        Xin, Fin, flen, Wi, bi, W1g, b1g, W2g, b2g, zT);
    readout_kernel<<<dim3(B_ROWS / 32), dim3(256), 0, stream>>>(
        zT, Fin, TRv, flen, Wr1, br1, Wr2, br2, Wr3, br3, outp);
}

// Round 8
// 273.536 us; speedup vs baseline: 6.7036x; 1.1140x over previous
//
#include <hip/hip_runtime.h>
#include <hip/hip_bf16.h>

// Problem constants (fixed by the reference)
#define B_ROWS 16384
#define L_SEQ  32

typedef _Float16 f16;
typedef __attribute__((ext_vector_type(8))) _Float16 f16x8;
typedef __attribute__((ext_vector_type(4))) float f32x4;
typedef __attribute__((ext_vector_type(4))) unsigned int u32x4;

// ---------- fast device math ----------
__device__ __forceinline__ unsigned pkh(float a, float b) {
    return __builtin_bit_cast(unsigned, __builtin_amdgcn_cvt_pkrtz(a, b));
}
__device__ __forceinline__ float tanh_fast(float x) {
    float e = __expf(2.0f * x);
    float r = __builtin_amdgcn_rcpf(e + 1.0f);
    return fmaf(-2.0f, r, 1.0f);
}
__device__ __forceinline__ float gelu_exact(float x) {
    return 0.5f * x * (1.0f + erff(x * 0.70710678118654752440f));
}
// opaque register pin: value becomes unknown-but-in-VGPR -> no remat/reload
__device__ __forceinline__ void pin4(u32x4& v) {
    unsigned x0 = v[0], x1 = v[1], x2 = v[2], x3 = v[3];
    asm volatile("" : "+v"(x0), "+v"(x1), "+v"(x2), "+v"(x3));
    v = (u32x4){x0, x1, x2, x3};
}

// ---------- Kernel 1: preprocessing + MFMA RK4 neural-ODE ----------
// One wave owns 16 rows (the 16 MFMA columns). Block = 4 waves = 64 rows.
// Layer-1 C-frag pair (2kk,2kk+1) IS layer-2's B-frag kk (validated r5/r7).
__global__ __launch_bounds__(256, 1) void ode_kernel(
    const float* __restrict__ Xin, const float* __restrict__ Fin,
    const int*   __restrict__ fa_len,
    const float* __restrict__ Wi,  const float* __restrict__ bi,
    const float* __restrict__ W1g, const float* __restrict__ b1g,
    const float* __restrict__ W2g, const float* __restrict__ b2g,
    float* __restrict__ zT)
{
    __shared__ __align__(16) float xm[64 * 132];   // [row][i<33][c<4], 528B row stride
#define XM(r_, i_, c_) xm[(r_) * 132 + (i_) * 4 + (c_)]

    const int tid = threadIdx.x;
    const int g16 = tid >> 4, sub = tid & 15;

    // ---- preprocessing (push_zeros + fill; identical to r5/r7) ----
    float mean_r[4]; int fl_r[4];
#pragma unroll
    for (int r = 0; r < 4; ++r) {
        const int row_l = g16 * 4 + r;
        const int row   = blockIdx.x * 64 + row_l;
        const float* Xr = Xin + row * L_SEQ;
        const float* Fr = Fin + row * L_SEQ;
        float xr0 = Xr[sub], xr1 = Xr[sub + 16];
        float fr0 = Fr[sub], fr1 = Fr[sub + 16];
        fl_r[r] = fa_len[row];
        float s = xr0 + xr1;
        s += __shfl_xor(s, 1, 16);
        s += __shfl_xor(s, 2, 16);
        s += __shfl_xor(s, 4, 16);
        s += __shfl_xor(s, 8, 16);
        mean_r[r] = s / (float)fl_r[r];
        XM(row_l, sub, 0)      = fr0; XM(row_l, sub, 1)      = xr0;
        XM(row_l, sub + 16, 0) = fr1; XM(row_l, sub + 16, 1) = xr1;
    }
    __syncthreads();

    float ff[4][2], xf[4][2];
#pragma unroll
    for (int r = 0; r < 4; ++r) {
        const int row_l = g16 * 4 + r;
        const int fl = fl_r[r];
        const float mean = mean_r[r];
        const int shift = L_SEQ - fl;
        int lsrc  = fl - 1 - shift;
        int lsrcC = lsrc < 0 ? 0 : lsrc;
        float lastX = (lsrc >= 0) ? (XM(row_l, lsrcC, 1) / mean) : 0.0f;
        float lastF = XM(row_l, fl - 1, 0);
#pragma unroll
        for (int u = 0; u < 2; ++u) {
            int p = sub + u * 16;
            int src = p - shift;
            int sc  = src < 0 ? 0 : src;
            float fraw = XM(row_l, sc, 0);
            float xraw = XM(row_l, sc, 1);
            ff[r][u] = (src >= 0) ? fraw : lastF;
            xf[r][u] = (src >= 0) ? (xraw / mean) : lastX;
        }
    }
    __syncthreads();
#pragma unroll
    for (int r = 0; r < 4; ++r) {
        const int row_l = g16 * 4 + r;
#pragma unroll
        for (int u = 0; u < 2; ++u) {
            int p = sub + u * 16;
            XM(row_l, p, 0) = ff[r][u];
            XM(row_l, p, 1) = xf[r][u];
        }
    }
    __syncthreads();
#pragma unroll
    for (int r = 0; r < 4; ++r) {
        const int row_l = g16 * 4 + r;
#pragma unroll
        for (int u = 0; u < 2; ++u) {
            int p = sub + u * 16;
            int qd = (p == 0) ? 1 : p;         // m[0] = x[1]-x[0]
            XM(row_l, p, 2) = XM(row_l, qd, 0) - XM(row_l, qd - 1, 0);
            XM(row_l, p, 3) = XM(row_l, qd, 1) - XM(row_l, qd - 1, 1);
        }
    }
    __syncthreads();

    // ---- MFMA-phase lane mapping ----
    const int wv   = tid >> 6;
    const int lane = tid & 63;
    const int n    = lane & 15;     // MFMA column = row-in-wave
    const int q    = lane >> 4;     // lane quarter
    const int rowl = wv * 16 + n;
    const int rowg = blockIdx.x * 64 + rowl;

    // Layer1 A = W1 K-padded to 32: k<8 = W1 row, k=8 = b1 (vs 1.0 on z side).
    u32x4 a1[16];
#pragma unroll
    for (int t = 0; t < 16; ++t) {
        const float* wr = W1g + (t * 16 + n) * 8 + (q < 2 ? q * 4 : 0);
        float4 w4 = *(const float4*)wr;
        float b1v = b1g[t * 16 + n];
        unsigned d0 = (q < 2) ? pkh(w4.x, w4.y) : (q == 2 ? pkh(b1v, 0.0f) : 0u);
        unsigned d1 = (q < 2) ? pkh(w4.z, w4.w) : 0u;
        a1[t] = (u32x4){d0, d1, 0u, 0u};
        pin4(a1[t]);                       // force VGPR residency (no remat)
    }
    // Layer2 A = W2 [16 x 256], 8 K-steps
    u32x4 a2[8];
#pragma unroll
    for (int kk = 0; kk < 8; ++kk) {
        const float* w2r = W2g + n * 256 + kk * 32 + 4 * q;
        float4 p0 = *(const float4*)(w2r);
        float4 p1 = *(const float4*)(w2r + 16);
        a2[kk] = (u32x4){pkh(p0.x, p0.y), pkh(p0.z, p0.w), pkh(p1.x, p1.y), pkh(p1.z, p1.w)};
        pin4(a2[kk]);                      // force VGPR residency (no remat)
    }
    // b2 seed for one layer2 chain (f32 exact)
    f32x4 c2seed;
#pragma unroll
    for (int r = 0; r < 4; ++r) c2seed[r] = b2g[4 * q + r];

    // z0 distributed: lane holds z[2q], z[2q+1] (f32 master)
    float f0 = XM(rowl, 0, 0), X0 = XM(rowl, 0, 1);
    float z0 = fmaf(Wi[(2 * q) * 2], f0, fmaf(Wi[(2 * q) * 2 + 1], X0, bi[2 * q]));
    float z1 = fmaf(Wi[(2 * q + 1) * 2], f0, fmaf(Wi[(2 * q + 1) * 2 + 1], X0, bi[2 * q + 1]));

    // bpermute byte-index: lane (q,n) gathers z-pairs from lanes (q&1)*32+n (+16)
    const int bpi = (((q & 1) << 5) + n) << 2;
    const f32x4 zero4 = {0.f, 0.f, 0.f, 0.f};
    const f16x8 zf16 = {0, 0, 0, 0, 0, 0, 0, 0};

    auto FEVAL = [&](float zza, float zzb, float d0c, float d1c, float& ko0, float& ko1) {
        // B(z) frag: 2 bpermutes; k=8 bias slot gets 1.0 for q==2
        unsigned myz = pkh(zza, zzb);
        int b0 = __builtin_amdgcn_ds_bpermute(bpi, (int)myz);
        int b1 = __builtin_amdgcn_ds_bpermute(bpi + 64, (int)myz);
        unsigned bz0 = (q < 2) ? (unsigned)b0 : (q == 2 ? 0x3C00u : 0u);
        unsigned bz1 = (q < 2) ? (unsigned)b1 : 0u;
        f16x8 bz = __builtin_bit_cast(f16x8, (u32x4){bz0, bz1, 0u, 0u});

        // layer 1: 16 independent MFMAs -> h tiles (C-frag, lane-local)
        f32x4 c1[16];
#pragma unroll
        for (int t = 0; t < 16; ++t)
            c1[t] = __builtin_amdgcn_mfma_f32_16x16x32_f16(
                __builtin_bit_cast(f16x8, a1[t]), bz, zero4, 0, 0, 0);

        // pack then packed-relu (f16 domain): C-frag pair (2kk,2kk+1) IS B-frag kk
        f16x8 hf[8];
#pragma unroll
        for (int kk = 0; kk < 8; ++kk) {
            u32x4 w = (u32x4){pkh(c1[2 * kk][0],     c1[2 * kk][1]),
                              pkh(c1[2 * kk][2],     c1[2 * kk][3]),
                              pkh(c1[2 * kk + 1][0], c1[2 * kk + 1][1]),
                              pkh(c1[2 * kk + 1][2], c1[2 * kk + 1][3])};
            hf[kk] = __builtin_elementwise_max(__builtin_bit_cast(f16x8, w), zf16);
        }

        // layer 2: two independent 4-MFMA chains (halves serial C-dep latency)
        f32x4 c2a = c2seed, c2b = zero4;
#pragma unroll
        for (int kk = 0; kk < 4; ++kk) {
            c2a = __builtin_amdgcn_mfma_f32_16x16x32_f16(
                __builtin_bit_cast(f16x8, a2[kk]), hf[kk], c2a, 0, 0, 0);
            c2b = __builtin_amdgcn_mfma_f32_16x16x32_f16(
                __builtin_bit_cast(f16x8, a2[kk + 4]), hf[kk + 4], c2b, 0, 0, 0);
        }
        f32x4 G = c2a + c2b;

        // g = tanh(G); lane holds G[4q..4q+3] -> k[2q], k[2q+1]
        float t0 = tanh_fast(G[0]), t1 = tanh_fast(G[1]);
        float t2 = tanh_fast(G[2]), t3 = tanh_fast(G[3]);
        ko0 = fmaf(t0, d0c, t1 * d1c);
        ko1 = fmaf(t2, d0c, t3 * d1c);
    };

    // ---- 31 intervals x 2 substeps of RK4 ----
#pragma unroll 1
    for (int i = 0; i < 31; ++i) {
        float4 P0 = *(const float4*)&XM(rowl, i, 0);
        float4 P1 = *(const float4*)&XM(rowl, i + 1, 0);
        float m0f = P0.z, m0X = P0.w, m1f = P1.z, m1X = P1.w;
        float df  = P0.x - P1.x, dXx = P0.y - P1.y;

        float d25f = fmaf(-1.125f, df,  fmaf(0.1875f, m0f, -0.3125f * m1f));
        float d25X = fmaf(-1.125f, dXx, fmaf(0.1875f, m0X, -0.3125f * m1X));
        float d50f = fmaf(-1.5f,   df,  fmaf(-0.25f,  m0f, -0.25f   * m1f));
        float d50X = fmaf(-1.5f,   dXx, fmaf(-0.25f,  m0X, -0.25f   * m1X));
        float d75f = fmaf(-1.125f, df,  fmaf(-0.3125f, m0f, 0.1875f * m1f));
        float d75X = fmaf(-1.125f, dXx, fmaf(-0.3125f, m0X, 0.1875f * m1X));

#pragma unroll 1
        for (int ssi = 0; ssi < 2; ++ssi) {
            float daf = ssi ? d50f : m0f,  daX = ssi ? d50X : m0X;
            float dbf = ssi ? d75f : d25f, dbX = ssi ? d75X : d25X;
            float ddf = ssi ? m1f  : d50f, ddX = ssi ? m1X  : d50X;

            float k1a, k1b, k2a, k2b, k3a, k3b, k4a, k4b, zza, zzb;
            FEVAL(z0, z1, daf, daX, k1a, k1b);
            zza = fmaf(0.25f, k1a, z0); zzb = fmaf(0.25f, k1b, z1);
            FEVAL(zza, zzb, dbf, dbX, k2a, k2b);
            zza = fmaf(0.25f, k2a, z0); zzb = fmaf(0.25f, k2b, z1);
            FEVAL(zza, zzb, dbf, dbX, k3a, k3b);
            zza = fmaf(0.5f, k3a, z0);  zzb = fmaf(0.5f, k3b, z1);
            FEVAL(zza, zzb, ddf, ddX, k4a, k4b);

            float ka = fmaf(2.f, k2a, k1a); ka = fmaf(2.f, k3a, ka);
            float kb = fmaf(2.f, k2b, k1b); kb = fmaf(2.f, k3b, kb);
            z0 = fmaf(1.f / 12.f, ka + k4a, z0);
            z1 = fmaf(1.f / 12.f, kb + k4b, z1);
        }
    }

    *(float2*)(zT + rowg * 8 + 2 * q) = make_float2(z0, z1);
#undef XM
}

// ---------- Kernel 2: MFMA readout (no LDS, no barriers) ----------
// Wave owns 16 rows (columns n). GEMM1: h1 = gelu(z@Wr1^T + br1), M=208pad.
// GEMM2: 13 M-tiles x 7 K-chunks(224pad) over Wr2; gelu + Wr3 dot in-register.
// Padding is exact: zero A-rows/bias -> gelu(0) = 0 -> zero contribution.
__global__ __launch_bounds__(256, 1) void readout_kernel(
    const float* __restrict__ zT,
    const float* __restrict__ Fin,
    const float* __restrict__ TRv,
    const int*   __restrict__ fa_len,
    const float* __restrict__ Wr1, const float* __restrict__ br1,
    const float* __restrict__ Wr2, const float* __restrict__ br2,
    const float* __restrict__ Wr3, const float* __restrict__ br3,
    float* __restrict__ out)
{
    const int tid  = threadIdx.x;
    const int wv   = tid >> 6;
    const int lane = tid & 63;
    const int n    = lane & 15;
    const int q    = lane >> 4;
    const int rowg = blockIdx.x * 64 + wv * 16 + n;

    const f32x4 zero4 = {0.f, 0.f, 0.f, 0.f};

    // ---- B-frag of z (K=8, bias 1.0 at k=8) ----
    u32x4 bzw = {0u, 0u, 0u, 0u};
    if (q < 2) {
        float4 z4 = *(const float4*)(zT + rowg * 8 + 4 * q);
        bzw[0] = pkh(z4.x, z4.y);
        bzw[1] = pkh(z4.z, z4.w);
    } else if (q == 2) {
        bzw[0] = 0x3C00u;               // (1.0, 0.0)
    }
    f16x8 bz = __builtin_bit_cast(f16x8, bzw);

    // ---- GEMM1: 13 tiles of h1 pre-activation ----
    f32x4 c1[13];
#pragma unroll
    for (int t = 0; t < 13; ++t) {
        int m = 16 * t + n;
        u32x4 af = {0u, 0u, 0u, 0u};
        if (q < 2) {
            if (m < 200) {
                float4 w4 = *(const float4*)(Wr1 + m * 8 + 4 * q);
                af[0] = pkh(w4.x, w4.y);
                af[1] = pkh(w4.z, w4.w);
            }
        } else if (q == 2) {
            float b = (m < 200) ? br1[m] : 0.0f;
            af[0] = pkh(b, 0.0f);
        }
        c1[t] = __builtin_amdgcn_mfma_f32_16x16x32_f16(
            __builtin_bit_cast(f16x8, af), bz, zero4, 0, 0, 0);
    }

    // ---- gelu + pack into B-frags for GEMM2 (C->B identity) ----
    f16x8 hf[7];
#pragma unroll
    for (int kk = 0; kk < 7; ++kk) {
        float g0 = gelu_exact(c1[2 * kk][0]), g1 = gelu_exact(c1[2 * kk][1]);
        float g2 = gelu_exact(c1[2 * kk][2]), g3 = gelu_exact(c1[2 * kk][3]);
        float g4 = 0.f, g5 = 0.f, g6 = 0.f, g7 = 0.f;
        if (kk < 6) {
            g4 = gelu_exact(c1[2 * kk + 1][0]); g5 = gelu_exact(c1[2 * kk + 1][1]);
            g6 = gelu_exact(c1[2 * kk + 1][2]); g7 = gelu_exact(c1[2 * kk + 1][3]);
        }
        u32x4 w = (u32x4){pkh(g0, g1), pkh(g2, g3), pkh(g4, g5), pkh(g6, g7)};
        hf[kk] = __builtin_bit_cast(f16x8, w);
    }

    // ---- GEMM2 + gelu + Wr3 dot, streamed over 13 M-tiles ----
    float tpart = 0.0f;
#pragma unroll 1
    for (int mt = 0; mt < 13; ++mt) {
        int mb = 16 * mt + 4 * q;       // this lane's 4 output rows
        f32x4 c2 = zero4;
        if (mb + 3 < 200) c2 = *(const f32x4*)(br2 + mb);
        int m2 = 16 * mt + n;           // A-row this lane loads
#pragma unroll
        for (int kk = 0; kk < 7; ++kk) {
            u32x4 af = {0u, 0u, 0u, 0u};
            if (m2 < 200) {
                int k0 = 32 * kk + 4 * q;
                const float* wr = Wr2 + m2 * 200 + k0;
                if (k0 + 3 < 200) {
                    float4 wa = *(const float4*)(wr);
                    af[0] = pkh(wa.x, wa.y); af[1] = pkh(wa.z, wa.w);
                }
                if (k0 + 19 < 200) {
                    float4 wb = *(const float4*)(wr + 16);
                    af[2] = pkh(wb.x, wb.y); af[3] = pkh(wb.z, wb.w);
                }
            }
            c2 = __builtin_amdgcn_mfma_f32_16x16x32_f16(
                __builtin_bit_cast(f16x8, af), hf[kk], c2, 0, 0, 0);
        }
        float4 w3 = make_float4(0.f, 0.f, 0.f, 0.f);
        if (mb + 3 < 200) w3 = *(const float4*)(Wr3 + mb);
        tpart = fmaf(w3.x, gelu_exact(c2[0]), tpart);
        tpart = fmaf(w3.y, gelu_exact(c2[1]), tpart);
        tpart = fmaf(w3.z, gelu_exact(c2[2]), tpart);
        tpart = fmaf(w3.w, gelu_exact(c2[3]), tpart);
    }
    // reduce over the 4 q-groups (rows m mod 16 partition)
    tpart += __shfl_xor(tpart, 16);
    tpart += __shfl_xor(tpart, 32);

    // ---- T10 -> E -> X_out (lane handles 8 columns p = 8q..8q+7) ----
    float tval = tpart + br3[0];
    float sig  = __fdividef(1.0f, 1.0f + __expf(-tval));
    float T10  = 0.1f + 6.9f * sig;
    float E    = __expf(-TRv[rowg] * __builtin_amdgcn_rcpf(T10));

    const float* Fr = Fin + rowg * 32 + 8 * q;
    float xo[8]; float ssum = 0.0f;
#pragma unroll
    for (int j = 0; j < 8; ++j) {
        float fa = Fr[j];
        float sn = __sinf(fa), cs = __cosf(fa);
        float v = __fdividef((1.0f - E) * sn, 1.0f - cs * E);
        xo[j] = v; ssum += v;
    }
    ssum += __shfl_xor(ssum, 16);
    ssum += __shfl_xor(ssum, 32);
    float mean2 = ssum / (float)fa_len[rowg];
    float inv   = __fdividef(1.0f, mean2);

    float4* dst = (float4*)(out + rowg * 32 + 8 * q);
    dst[0] = make_float4(xo[0] * inv, xo[1] * inv, xo[2] * inv, xo[3] * inv);
    dst[1] = make_float4(xo[4] * inv, xo[5] * inv, xo[6] * inv, xo[7] * inv);
    if (q == 0) {
        out[B_ROWS * L_SEQ + rowg] = T10;
        out[B_ROWS * L_SEQ + B_ROWS + rowg] = 1.0f;
    }
}

extern "C" void kernel_launch(void* const* d_in, const int* in_sizes, int n_in,
                              void* d_out, int out_size, void* d_ws, size_t ws_size,
                              hipStream_t stream) {
    const float* Xin  = (const float*)d_in[0];
    const float* Fin  = (const float*)d_in[1];
    const float* TRv  = (const float*)d_in[2];
    const float* Wi   = (const float*)d_in[3];
    const float* bi   = (const float*)d_in[4];
    const float* W1g  = (const float*)d_in[5];
    const float* b1g  = (const float*)d_in[6];
    const float* W2g  = (const float*)d_in[7];
    const float* b2g  = (const float*)d_in[8];
    const float* Wr1  = (const float*)d_in[9];
    const float* br1  = (const float*)d_in[10];
    const float* Wr2  = (const float*)d_in[11];
    const float* br2  = (const float*)d_in[12];
    const float* Wr3  = (const float*)d_in[13];
    const float* br3  = (const float*)d_in[14];
    const int*   flen = (const int*)d_in[16];

    float* outp = (float*)d_out;
    float* zT   = (float*)d_ws;

    ode_kernel<<<dim3(B_ROWS / 64), dim3(256), 0, stream>>>(
        Xin, Fin, flen, Wi, bi, W1g, b1g, W2g, b2g, zT);
    readout_kernel<<<dim3(B_ROWS / 64), dim3(256), 0, stream>>>(
        zT, Fin, TRv, flen, Wr1, br1, Wr2, br2, Wr3, br3, outp);
}

// Round 9
// 251.745 us; speedup vs baseline: 7.2838x; 1.0866x over previous
//
#include <hip/hip_runtime.h>
#include <hip/hip_bf16.h>

// Problem constants (fixed by the reference)
#define B_ROWS 16384
#define L_SEQ  32

typedef _Float16 f16;
typedef __attribute__((ext_vector_type(8))) _Float16 f16x8;
typedef __attribute__((ext_vector_type(4))) float f32x4;
typedef __attribute__((ext_vector_type(4))) unsigned int u32x4;

// ---------- fast device math ----------
__device__ __forceinline__ unsigned pkh(float a, float b) {
    return __builtin_bit_cast(unsigned, __builtin_amdgcn_cvt_pkrtz(a, b));
}
__device__ __forceinline__ float tanh_fast(float x) {
    float e = __expf(2.0f * x);
    float r = __builtin_amdgcn_rcpf(e + 1.0f);
    return fmaf(-2.0f, r, 1.0f);
}
__device__ __forceinline__ float gelu_exact(float x) {
    return 0.5f * x * (1.0f + erff(x * 0.70710678118654752440f));
}
// opaque register pin: value becomes unknown-but-in-VGPR -> no remat/reload
__device__ __forceinline__ void pin4(u32x4& v) {
    unsigned x0 = v[0], x1 = v[1], x2 = v[2], x3 = v[3];
    asm volatile("" : "+v"(x0), "+v"(x1), "+v"(x2), "+v"(x3));
    v = (u32x4){x0, x1, x2, x3};
}

// ---------- Fused kernel: preprocessing + MFMA RK4 ODE + MFMA readout ----------
// One wave owns 16 rows (the 16 MFMA columns). Block = 4 waves = 64 rows.
// Layer-1 C-frag pair (2kk,2kk+1) IS layer-2's B-frag kk (HW-validated r5-r8).
// After RK4 the wave's z registers feed the readout GEMMs directly (the ode
// bpermute gather IS the readout B-frag constructor). Wr2 staged in LDS (f16,
// row stride 232: 464B = 20 dwords mod 32 -> 2-way bank alias, free).
#define W2S_STRIDE 232
__global__ __launch_bounds__(256, 1) void fused_kernel(
    const float* __restrict__ Xin, const float* __restrict__ Fin,
    const float* __restrict__ TRv,
    const int*   __restrict__ fa_len,
    const float* __restrict__ Wi,  const float* __restrict__ bi,
    const float* __restrict__ W1g, const float* __restrict__ b1g,
    const float* __restrict__ W2g, const float* __restrict__ b2g,
    const float* __restrict__ Wr1, const float* __restrict__ br1,
    const float* __restrict__ Wr2, const float* __restrict__ br2,
    const float* __restrict__ Wr3, const float* __restrict__ br3,
    float* __restrict__ out)
{
    __shared__ __align__(16) float xm[64 * 132];                 // 33792 B
    __shared__ __align__(16) unsigned short w2s[208 * W2S_STRIDE]; // 96512 B
#define XM(r_, i_, c_) xm[(r_) * 132 + (i_) * 4 + (c_)]

    const int tid = threadIdx.x;
    const int g16 = tid >> 4, sub = tid & 15;

    // ---- Phase 0: stage Wr2 -> LDS f16 (+ zero padding) ----
    {
        const float4* src = (const float4*)Wr2;
#pragma unroll 4
        for (int v = tid; v < 10000; v += 256) {
            int row = v / 50, c = (v - row * 50) * 4;
            float4 w = src[v];
            *(uint2*)(&w2s[row * W2S_STRIDE + c]) =
                make_uint2(pkh(w.x, w.y), pkh(w.z, w.w));
        }
        for (int idx = tid; idx < 8 * W2S_STRIDE; idx += 256)
            w2s[200 * W2S_STRIDE + idx] = 0;
        for (int idx = tid; idx < 200 * 24; idx += 256) {
            int row = idx / 24, c = 200 + (idx - row * 24);
            w2s[row * W2S_STRIDE + c] = 0;
        }
    }

    // ---- Phase 1: preprocessing (push_zeros + fill; identical to r8) ----
    float mean_r[4]; int fl_r[4];
#pragma unroll
    for (int r = 0; r < 4; ++r) {
        const int row_l = g16 * 4 + r;
        const int row   = blockIdx.x * 64 + row_l;
        const float* Xr = Xin + row * L_SEQ;
        const float* Fr = Fin + row * L_SEQ;
        float xr0 = Xr[sub], xr1 = Xr[sub + 16];
        float fr0 = Fr[sub], fr1 = Fr[sub + 16];
        fl_r[r] = fa_len[row];
        float s = xr0 + xr1;
        s += __shfl_xor(s, 1, 16);
        s += __shfl_xor(s, 2, 16);
        s += __shfl_xor(s, 4, 16);
        s += __shfl_xor(s, 8, 16);
        mean_r[r] = s / (float)fl_r[r];
        XM(row_l, sub, 0)      = fr0; XM(row_l, sub, 1)      = xr0;
        XM(row_l, sub + 16, 0) = fr1; XM(row_l, sub + 16, 1) = xr1;
    }
    __syncthreads();

    float ff[4][2], xf[4][2];
#pragma unroll
    for (int r = 0; r < 4; ++r) {
        const int row_l = g16 * 4 + r;
        const int fl = fl_r[r];
        const float mean = mean_r[r];
        const int shift = L_SEQ - fl;
        int lsrc  = fl - 1 - shift;
        int lsrcC = lsrc < 0 ? 0 : lsrc;
        float lastX = (lsrc >= 0) ? (XM(row_l, lsrcC, 1) / mean) : 0.0f;
        float lastF = XM(row_l, fl - 1, 0);
#pragma unroll
        for (int u = 0; u < 2; ++u) {
            int p = sub + u * 16;
            int src = p - shift;
            int sc  = src < 0 ? 0 : src;
            float fraw = XM(row_l, sc, 0);
            float xraw = XM(row_l, sc, 1);
            ff[r][u] = (src >= 0) ? fraw : lastF;
            xf[r][u] = (src >= 0) ? (xraw / mean) : lastX;
        }
    }
    __syncthreads();
#pragma unroll
    for (int r = 0; r < 4; ++r) {
        const int row_l = g16 * 4 + r;
#pragma unroll
        for (int u = 0; u < 2; ++u) {
            int p = sub + u * 16;
            XM(row_l, p, 0) = ff[r][u];
            XM(row_l, p, 1) = xf[r][u];
        }
    }
    __syncthreads();
#pragma unroll
    for (int r = 0; r < 4; ++r) {
        const int row_l = g16 * 4 + r;
#pragma unroll
        for (int u = 0; u < 2; ++u) {
            int p = sub + u * 16;
            int qd = (p == 0) ? 1 : p;         // m[0] = x[1]-x[0]
            XM(row_l, p, 2) = XM(row_l, qd, 0) - XM(row_l, qd - 1, 0);
            XM(row_l, p, 3) = XM(row_l, qd, 1) - XM(row_l, qd - 1, 1);
        }
    }
    __syncthreads();

    // ---- MFMA-phase lane mapping ----
    const int wv   = tid >> 6;
    const int lane = tid & 63;
    const int n    = lane & 15;     // MFMA column = row-in-wave
    const int q    = lane >> 4;     // lane quarter
    const int rowl = wv * 16 + n;
    const int rowg = blockIdx.x * 64 + rowl;

    // Layer1 A = W1 K-padded to 32: k<8 = W1 row, k=8 = b1 (vs 1.0 on z side).
    u32x4 a1[16];
#pragma unroll
    for (int t = 0; t < 16; ++t) {
        const float* wr = W1g + (t * 16 + n) * 8 + (q < 2 ? q * 4 : 0);
        float4 w4 = *(const float4*)wr;
        float b1v = b1g[t * 16 + n];
        unsigned d0 = (q < 2) ? pkh(w4.x, w4.y) : (q == 2 ? pkh(b1v, 0.0f) : 0u);
        unsigned d1 = (q < 2) ? pkh(w4.z, w4.w) : 0u;
        a1[t] = (u32x4){d0, d1, 0u, 0u};
        pin4(a1[t]);                       // force VGPR residency (no remat)
    }
    // Layer2 A = W2 [16 x 256], 8 K-steps
    u32x4 a2[8];
#pragma unroll
    for (int kk = 0; kk < 8; ++kk) {
        const float* w2r = W2g + n * 256 + kk * 32 + 4 * q;
        float4 p0 = *(const float4*)(w2r);
        float4 p1 = *(const float4*)(w2r + 16);
        a2[kk] = (u32x4){pkh(p0.x, p0.y), pkh(p0.z, p0.w), pkh(p1.x, p1.y), pkh(p1.z, p1.w)};
        pin4(a2[kk]);                      // force VGPR residency (no remat)
    }
    // b2 seed for one layer2 chain (f32 exact)
    f32x4 c2seed;
#pragma unroll
    for (int r = 0; r < 4; ++r) c2seed[r] = b2g[4 * q + r];

    // z0 distributed: lane holds z[2q], z[2q+1] (f32 master)
    float f0 = XM(rowl, 0, 0), X0 = XM(rowl, 0, 1);
    float z0 = fmaf(Wi[(2 * q) * 2], f0, fmaf(Wi[(2 * q) * 2 + 1], X0, bi[2 * q]));
    float z1 = fmaf(Wi[(2 * q + 1) * 2], f0, fmaf(Wi[(2 * q + 1) * 2 + 1], X0, bi[2 * q + 1]));

    // bpermute byte-index: lane (q,n) gathers z-pairs from lanes (q&1)*32+n (+16)
    const int bpi = (((q & 1) << 5) + n) << 2;
    const f32x4 zero4 = {0.f, 0.f, 0.f, 0.f};
    const f16x8 zf16 = {0, 0, 0, 0, 0, 0, 0, 0};

    // B(z) fragment constructor (also used by the readout GEMM1)
    auto make_bz = [&](float zza, float zzb) -> f16x8 {
        unsigned myz = pkh(zza, zzb);
        int b0 = __builtin_amdgcn_ds_bpermute(bpi, (int)myz);
        int b1 = __builtin_amdgcn_ds_bpermute(bpi + 64, (int)myz);
        unsigned bz0 = (q < 2) ? (unsigned)b0 : (q == 2 ? 0x3C00u : 0u);
        unsigned bz1 = (q < 2) ? (unsigned)b1 : 0u;
        return __builtin_bit_cast(f16x8, (u32x4){bz0, bz1, 0u, 0u});
    };

    auto FEVAL = [&](float zza, float zzb, float d0c, float d1c, float& ko0, float& ko1) {
        f16x8 bz = make_bz(zza, zzb);

        // layer 1: 16 independent MFMAs -> h tiles (C-frag, lane-local)
        f32x4 c1[16];
#pragma unroll
        for (int t = 0; t < 16; ++t)
            c1[t] = __builtin_amdgcn_mfma_f32_16x16x32_f16(
                __builtin_bit_cast(f16x8, a1[t]), bz, zero4, 0, 0, 0);

        // pack then packed-relu (f16 domain): C-frag pair (2kk,2kk+1) IS B-frag kk
        f16x8 hf[8];
#pragma unroll
        for (int kk = 0; kk < 8; ++kk) {
            u32x4 w = (u32x4){pkh(c1[2 * kk][0],     c1[2 * kk][1]),
                              pkh(c1[2 * kk][2],     c1[2 * kk][3]),
                              pkh(c1[2 * kk + 1][0], c1[2 * kk + 1][1]),
                              pkh(c1[2 * kk + 1][2], c1[2 * kk + 1][3])};
            hf[kk] = __builtin_elementwise_max(__builtin_bit_cast(f16x8, w), zf16);
        }

        // layer 2: two independent 4-MFMA chains (halves serial C-dep latency)
        f32x4 c2a = c2seed, c2b = zero4;
#pragma unroll
        for (int kk = 0; kk < 4; ++kk) {
            c2a = __builtin_amdgcn_mfma_f32_16x16x32_f16(
                __builtin_bit_cast(f16x8, a2[kk]), hf[kk], c2a, 0, 0, 0);
            c2b = __builtin_amdgcn_mfma_f32_16x16x32_f16(
                __builtin_bit_cast(f16x8, a2[kk + 4]), hf[kk + 4], c2b, 0, 0, 0);
        }
        f32x4 G = c2a + c2b;

        // g = tanh(G); lane holds G[4q..4q+3] -> k[2q], k[2q+1]
        float t0 = tanh_fast(G[0]), t1 = tanh_fast(G[1]);
        float t2 = tanh_fast(G[2]), t3 = tanh_fast(G[3]);
        ko0 = fmaf(t0, d0c, t1 * d1c);
        ko1 = fmaf(t2, d0c, t3 * d1c);
    };

    // ---- Phase 2: 31 intervals x 2 substeps of RK4 ----
#pragma unroll 1
    for (int i = 0; i < 31; ++i) {
        float4 P0 = *(const float4*)&XM(rowl, i, 0);
        float4 P1 = *(const float4*)&XM(rowl, i + 1, 0);
        float m0f = P0.z, m0X = P0.w, m1f = P1.z, m1X = P1.w;
        float df  = P0.x - P1.x, dXx = P0.y - P1.y;

        float d25f = fmaf(-1.125f, df,  fmaf(0.1875f, m0f, -0.3125f * m1f));
        float d25X = fmaf(-1.125f, dXx, fmaf(0.1875f, m0X, -0.3125f * m1X));
        float d50f = fmaf(-1.5f,   df,  fmaf(-0.25f,  m0f, -0.25f   * m1f));
        float d50X = fmaf(-1.5f,   dXx, fmaf(-0.25f,  m0X, -0.25f   * m1X));
        float d75f = fmaf(-1.125f, df,  fmaf(-0.3125f, m0f, 0.1875f * m1f));
        float d75X = fmaf(-1.125f, dXx, fmaf(-0.3125f, m0X, 0.1875f * m1X));

#pragma unroll 1
        for (int ssi = 0; ssi < 2; ++ssi) {
            float daf = ssi ? d50f : m0f,  daX = ssi ? d50X : m0X;
            float dbf = ssi ? d75f : d25f, dbX = ssi ? d75X : d25X;
            float ddf = ssi ? m1f  : d50f, ddX = ssi ? m1X  : d50X;

            float k1a, k1b, k2a, k2b, k3a, k3b, k4a, k4b, zza, zzb;
            FEVAL(z0, z1, daf, daX, k1a, k1b);
            zza = fmaf(0.25f, k1a, z0); zzb = fmaf(0.25f, k1b, z1);
            FEVAL(zza, zzb, dbf, dbX, k2a, k2b);
            zza = fmaf(0.25f, k2a, z0); zzb = fmaf(0.25f, k2b, z1);
            FEVAL(zza, zzb, dbf, dbX, k3a, k3b);
            zza = fmaf(0.5f, k3a, z0);  zzb = fmaf(0.5f, k3b, z1);
            FEVAL(zza, zzb, ddf, ddX, k4a, k4b);

            float ka = fmaf(2.f, k2a, k1a); ka = fmaf(2.f, k3a, ka);
            float kb = fmaf(2.f, k2b, k1b); kb = fmaf(2.f, k3b, kb);
            z0 = fmaf(1.f / 12.f, ka + k4a, z0);
            z1 = fmaf(1.f / 12.f, kb + k4b, z1);
        }
    }

    // ---- Phase 3: readout (in-register; z already distributed correctly) ----
    // GEMM1: h1 pre-activation, 13 M-tiles over Wr1 (M=208 pad)
    f16x8 bz = make_bz(z0, z1);
    f32x4 c1r[13];
#pragma unroll
    for (int t = 0; t < 13; ++t) {
        int m = 16 * t + n;
        u32x4 af = {0u, 0u, 0u, 0u};
        if (q < 2) {
            if (m < 200) {
                float4 w4 = *(const float4*)(Wr1 + m * 8 + 4 * q);
                af[0] = pkh(w4.x, w4.y);
                af[1] = pkh(w4.z, w4.w);
            }
        } else if (q == 2) {
            float b = (m < 200) ? br1[m] : 0.0f;
            af[0] = pkh(b, 0.0f);
        }
        c1r[t] = __builtin_amdgcn_mfma_f32_16x16x32_f16(
            __builtin_bit_cast(f16x8, af), bz, zero4, 0, 0, 0);
    }

    // gelu + pack into B-frags for GEMM2 (C->B identity)
    f16x8 hf2[7];
#pragma unroll
    for (int kk = 0; kk < 7; ++kk) {
        float g0 = gelu_exact(c1r[2 * kk][0]), g1 = gelu_exact(c1r[2 * kk][1]);
        float g2 = gelu_exact(c1r[2 * kk][2]), g3 = gelu_exact(c1r[2 * kk][3]);
        float g4 = 0.f, g5 = 0.f, g6 = 0.f, g7 = 0.f;
        if (kk < 6) {
            g4 = gelu_exact(c1r[2 * kk + 1][0]); g5 = gelu_exact(c1r[2 * kk + 1][1]);
            g6 = gelu_exact(c1r[2 * kk + 1][2]); g7 = gelu_exact(c1r[2 * kk + 1][3]);
        }
        u32x4 w = (u32x4){pkh(g0, g1), pkh(g2, g3), pkh(g4, g5), pkh(g6, g7)};
        hf2[kk] = __builtin_bit_cast(f16x8, w);
    }

    // GEMM2 from LDS-staged Wr2 + gelu + Wr3 dot, streamed over 13 M-tiles
    float tpart = 0.0f;
#pragma unroll 1
    for (int mt = 0; mt < 13; ++mt) {
        int mb = 16 * mt + 4 * q;       // this lane's 4 output rows
        f32x4 c2 = zero4;
        if (mb + 3 < 200) c2 = *(const f32x4*)(br2 + mb);
        const unsigned short* ap = &w2s[(16 * mt + n) * W2S_STRIDE + 4 * q];
#pragma unroll
        for (int kk = 0; kk < 7; ++kk) {
            uint2 lo = *(const uint2*)(ap + 32 * kk);
            uint2 hi = *(const uint2*)(ap + 32 * kk + 16);
            u32x4 af = {lo.x, lo.y, hi.x, hi.y};
            c2 = __builtin_amdgcn_mfma_f32_16x16x32_f16(
                __builtin_bit_cast(f16x8, af), hf2[kk], c2, 0, 0, 0);
        }
        float4 w3 = make_float4(0.f, 0.f, 0.f, 0.f);
        if (mb + 3 < 200) w3 = *(const float4*)(Wr3 + mb);
        tpart = fmaf(w3.x, gelu_exact(c2[0]), tpart);
        tpart = fmaf(w3.y, gelu_exact(c2[1]), tpart);
        tpart = fmaf(w3.z, gelu_exact(c2[2]), tpart);
        tpart = fmaf(w3.w, gelu_exact(c2[3]), tpart);
    }
    // reduce over the 4 q-groups (rows m mod 16 partition)
    tpart += __shfl_xor(tpart, 16);
    tpart += __shfl_xor(tpart, 32);

    // T10 -> E -> X_out (lane handles 8 columns p = 8q..8q+7)
    float tval = tpart + br3[0];
    float sig  = __fdividef(1.0f, 1.0f + __expf(-tval));
    float T10  = 0.1f + 6.9f * sig;
    float E    = __expf(-TRv[rowg] * __builtin_amdgcn_rcpf(T10));

    const float* Fr = Fin + rowg * 32 + 8 * q;
    float xo[8]; float ssum = 0.0f;
#pragma unroll
    for (int j = 0; j < 8; ++j) {
        float fa = Fr[j];
        float sn = __sinf(fa), cs = __cosf(fa);
        float v = __fdividef((1.0f - E) * sn, 1.0f - cs * E);
        xo[j] = v; ssum += v;
    }
    ssum += __shfl_xor(ssum, 16);
    ssum += __shfl_xor(ssum, 32);
    float mean2 = ssum / (float)fa_len[rowg];
    float inv   = __fdividef(1.0f, mean2);

    float4* dst = (float4*)(out + rowg * 32 + 8 * q);
    dst[0] = make_float4(xo[0] * inv, xo[1] * inv, xo[2] * inv, xo[3] * inv);
    dst[1] = make_float4(xo[4] * inv, xo[5] * inv, xo[6] * inv, xo[7] * inv);
    if (q == 0) {
        out[B_ROWS * L_SEQ + rowg] = T10;
        out[B_ROWS * L_SEQ + B_ROWS + rowg] = 1.0f;
    }
#undef XM
}

extern "C" void kernel_launch(void* const* d_in, const int* in_sizes, int n_in,
                              void* d_out, int out_size, void* d_ws, size_t ws_size,
                              hipStream_t stream) {
    const float* Xin  = (const float*)d_in[0];
    const float* Fin  = (const float*)d_in[1];
    const float* TRv  = (const float*)d_in[2];
    const float* Wi   = (const float*)d_in[3];
    const float* bi   = (const float*)d_in[4];
    const float* W1g  = (const float*)d_in[5];
    const float* b1g  = (const float*)d_in[6];
    const float* W2g  = (const float*)d_in[7];
    const float* b2g  = (const float*)d_in[8];
    const float* Wr1  = (const float*)d_in[9];
    const float* br1  = (const float*)d_in[10];
    const float* Wr2  = (const float*)d_in[11];
    const float* br2  = (const float*)d_in[12];
    const float* Wr3  = (const float*)d_in[13];
    const float* br3  = (const float*)d_in[14];
    const int*   flen = (const int*)d_in[16];

    float* outp = (float*)d_out;
    (void)d_ws; (void)ws_size;

    fused_kernel<<<dim3(B_ROWS / 64), dim3(256), 0, stream>>>(
        Xin, Fin, TRv, flen, Wi, bi, W1g, b1g, W2g, b2g,
        Wr1, br1, Wr2, br2, Wr3, br3, outp);
}